// Round 2
// baseline (931.470 us; speedup 1.0000x reference)
//
#include <hip/hip_runtime.h>

// MultiHeadVectorAttention — f32 correctness baseline (inputs/outputs are float32).
// bs=2, n=1024, H=8, DH=64, K=16, EMB=INNER=512, AINNER=256, POSH=64.
// Workspace (floats): D(1M) V(1M) agg(1M) nrm(16K) npart(128K) nbr(32K int) attn(16.7M) ~= 80.4 MB.

#define BS 2
#define NPT 1024
#define HH 8
#define DH 64
#define KNN 16
#define EMB 512
#define INNER 512
#define AINNER 256
#define POSH 64

// ---- K1: projections. D = query@wq - key@wk, V = value@wv, stored (b,h,i,d) f32.
__global__ __launch_bounds__(256) void k_proj(const float* __restrict__ query,
                                              const float* __restrict__ key_in,
                                              const float* __restrict__ value,
                                              const float* __restrict__ wq,
                                              const float* __restrict__ wk,
                                              const float* __restrict__ wv,
                                              float* __restrict__ Dws,
                                              float* __restrict__ Vws)
{
    __shared__ float qs[8][EMB], ks[8][EMB], vs[8][EMB];
    const int t = threadIdx.x;
    const int g0 = blockIdx.x * 8;
    for (int v = t; v < 8 * 128; v += 256) {
        int r = v >> 7, c4 = v & 127;
        ((float4*)qs[r])[c4] = ((const float4*)(query  + (size_t)(g0 + r) * EMB))[c4];
        ((float4*)ks[r])[c4] = ((const float4*)(key_in + (size_t)(g0 + r) * EMB))[c4];
        ((float4*)vs[r])[c4] = ((const float4*)(value  + (size_t)(g0 + r) * EMB))[c4];
    }
    __syncthreads();
    float aD0[8] = {}, aD1[8] = {}, aV0[8] = {}, aV1[8] = {};
    for (int e = 0; e < EMB; ++e) {
        float2 wqe = ((const float2*)(wq + (size_t)e * INNER))[t];
        float2 wke = ((const float2*)(wk + (size_t)e * INNER))[t];
        float2 wve = ((const float2*)(wv + (size_t)e * INNER))[t];
        #pragma unroll
        for (int r = 0; r < 8; ++r) {
            float qe = qs[r][e], ke = ks[r][e], ve = vs[r][e];
            aD0[r] = fmaf(qe, wqe.x, aD0[r]); aD0[r] = fmaf(-ke, wke.x, aD0[r]);
            aD1[r] = fmaf(qe, wqe.y, aD1[r]); aD1[r] = fmaf(-ke, wke.y, aD1[r]);
            aV0[r] = fmaf(ve, wve.x, aV0[r]);
            aV1[r] = fmaf(ve, wve.y, aV1[r]);
        }
    }
    const int c0 = 2 * t;
    const int h = c0 >> 6, d0 = c0 & 63;
    #pragma unroll
    for (int r = 0; r < 8; ++r) {
        int g = g0 + r;
        int b = g >> 10, i = g & 1023;
        size_t off = (((size_t)(b * HH + h)) * NPT + i) * DH + d0;
        *(float2*)&Dws[off] = make_float2(aD0[r], aD1[r]);
        *(float2*)&Vws[off] = make_float2(aV0[r], aV1[r]);
    }
}

// ---- K2: KNN, 16 smallest d2 per (b,i), ties -> lowest index (stable top_k).
__global__ __launch_bounds__(256) void k_knn(const float* __restrict__ canonical, int* __restrict__ nbr)
{
    const int i = blockIdx.x, b = blockIdx.y, t = threadIdx.x;
    __shared__ float d2[NPT];
    __shared__ float redv[256];
    __shared__ int   redi[256];
    const float* cb = canonical + (size_t)b * NPT * 3;
    const float xi = cb[i*3+0], yi = cb[i*3+1], zi = cb[i*3+2];
    for (int j = t; j < NPT; j += 256) {
        float dx = __fsub_rn(cb[j*3+0], xi);
        float dy = __fsub_rn(cb[j*3+1], yi);
        float dz = __fsub_rn(cb[j*3+2], zi);
        // no FMA contraction, (x^2+y^2)+z^2 order
        d2[j] = __fadd_rn(__fadd_rn(__fmul_rn(dx,dx), __fmul_rn(dy,dy)), __fmul_rn(dz,dz));
    }
    __syncthreads();
    for (int sel = 0; sel < KNN; ++sel) {
        float bv = __builtin_inff(); int bi = NPT;
        for (int j = t; j < NPT; j += 256) {
            float v = d2[j];
            if (v < bv) { bv = v; bi = j; }   // ascending j: ties keep first
        }
        redv[t] = bv; redi[t] = bi;
        __syncthreads();
        for (int s = 128; s > 0; s >>= 1) {
            if (t < s) {
                float v2 = redv[t+s]; int i2 = redi[t+s];
                float v1 = redv[t];   int i1 = redi[t];
                if (v2 < v1 || (v2 == v1 && i2 < i1)) { redv[t] = v2; redi[t] = i2; }
            }
            __syncthreads();
        }
        if (t == 0) { nbr[((size_t)b*NPT + i)*KNN + sel] = redi[0]; d2[redi[0]] = __builtin_inff(); }
        __syncthreads();
    }
}

// ---- K3: per-head attn MLP + softmax over j. rpe recomputed in-kernel (h-slice).
// Block = (it in [0,128), h, b) covering i = it*8 .. it*8+7.
__global__ __launch_bounds__(256) void k_attn(const float* __restrict__ Dws,
                                              const float* __restrict__ canonical,
                                              const int* __restrict__ nbr,
                                              const float* __restrict__ pw1,
                                              const float* __restrict__ pb1,
                                              const float* __restrict__ pw2,
                                              const float* __restrict__ pb2,
                                              const float* __restrict__ aw1,
                                              const float* __restrict__ ab1,
                                              const float* __restrict__ aw2,
                                              const float* __restrict__ ab2,
                                              float* __restrict__ attn)
{
    const int it = blockIdx.x, h = blockIdx.y, b = blockIdx.z, t = threadIdx.x;
    __shared__ float xs[KNN * DH];        // 4 KB
    __shared__ float hs[KNN * AINNER];    // 16 KB
    __shared__ float part[4 * KNN * DH];  // 16 KB
    __shared__ float sims[KNN * DH];      // 4 KB
    __shared__ float w2h[POSH * DH];      // 16 KB: pos_w2[p][h*64+d]
    __shared__ float h1[KNN * POSH];      // 4 KB
    __shared__ float pw1s[3 * POSH];
    __shared__ float pb1s[POSH];
    __shared__ float pb2h[DH];
    __shared__ float ab2s[DH];
    __shared__ float rel[KNN][3];
    __shared__ int nbrrow[KNN];

    // attn-MLP weights in registers: thread e=t owns aw1[h][e][0..63];
    // thread (d=t&63, p4=t>>6) owns aw2[h][d][p4*64 .. +63].
    float4 w1r[16], w2r[16];
    {
        const float4* p1 = (const float4*)(aw1 + ((size_t)h * AINNER + t) * DH);
        #pragma unroll
        for (int c = 0; c < 16; ++c) w1r[c] = p1[c];
        const float4* p2 = (const float4*)(aw2 + ((size_t)h * DH + (t & 63)) * AINNER + (t >> 6) * 64);
        #pragma unroll
        for (int c = 0; c < 16; ++c) w2r[c] = p2[c];
    }
    const float ab1v = ab1[h * AINNER + t];
    for (int v = t; v < POSH * DH; v += 256)
        w2h[v] = pw2[(size_t)(v >> 6) * INNER + h * DH + (v & 63)];
    if (t < 192) pw1s[t] = pw1[t];
    if (t < 64) { pb1s[t] = pb1[t]; pb2h[t] = pb2[h * DH + t]; ab2s[t] = ab2[h * DH + t]; }
    if (t < KNN) nbrrow[t] = nbr[((size_t)b * NPT + h * 128 + it) * KNN + t];
    __syncthreads();

    for (int ti = 0; ti < 8; ++ti) {
        const int i = it * 8 + ti;
        if (t < KNN) {
            int nv2 = nbr[((size_t)b * NPT + i) * KNN + t];
            const float* cn = canonical + ((size_t)b * NPT + nv2) * 3;
            const float* ci = canonical + ((size_t)b * NPT + i) * 3;
            rel[t][0] = cn[0] - ci[0];
            rel[t][1] = cn[1] - ci[1];
            rel[t][2] = cn[2] - ci[2];
        }
        __syncthreads();
        // h1[j][p] = relu(pb1 + rel @ pw1)
        for (int r = 0; r < 4; ++r) {
            int v = r * 256 + t; int j = v >> 6; int p = v & 63;
            float a = pb1s[p];
            a = fmaf(rel[j][0], pw1s[p], a);
            a = fmaf(rel[j][1], pw1s[64 + p], a);
            a = fmaf(rel[j][2], pw1s[128 + p], a);
            h1[v] = fmaxf(a, 0.0f);
        }
        __syncthreads();
        // xs[j][d] = D[gathered] + rpe_h[j][d]
        for (int r = 0; r < 4; ++r) {
            int v = r * 256 + t; int j = v >> 6; int d = v & 63;
            int nv = nbrrow[2 * ti + (j >> 3)];
            float dv = Dws[(((size_t)b * HH + (nv >> 7)) * NPT + (nv & 127) * 8 + (j & 7)) * DH + d];
            float rp = pb2h[d];
            #pragma unroll
            for (int p = 0; p < POSH; ++p) rp = fmaf(h1[j * POSH + p], w2h[p * DH + d], rp);
            xs[v] = dv + rp;
        }
        __syncthreads();
        // MLP1: hidden[e=t][j]
        float acc[KNN];
        #pragma unroll
        for (int j = 0; j < KNN; ++j) acc[j] = ab1v;
        #pragma unroll
        for (int c = 0; c < 16; ++c) {
            float4 w = w1r[c];
            #pragma unroll
            for (int j = 0; j < KNN; ++j) {
                float4 xv = *(const float4*)&xs[j * DH + c * 4];
                acc[j] = fmaf(xv.w, w.w, fmaf(xv.z, w.z, fmaf(xv.y, w.y, fmaf(xv.x, w.x, acc[j]))));
            }
        }
        #pragma unroll
        for (int j = 0; j < KNN; ++j) hs[j * AINNER + t] = fmaxf(acc[j], 0.0f);
        __syncthreads();
        // MLP2 partials: thread (d = t&63, p4 = t>>6)
        #pragma unroll
        for (int j = 0; j < KNN; ++j) acc[j] = 0.0f;
        const int p64 = (t >> 6) * 64;
        #pragma unroll
        for (int c = 0; c < 16; ++c) {
            float4 w = w2r[c];
            #pragma unroll
            for (int j = 0; j < KNN; ++j) {
                float4 hv = *(const float4*)&hs[j * AINNER + p64 + c * 4];
                acc[j] = fmaf(hv.w, w.w, fmaf(hv.z, w.z, fmaf(hv.y, w.y, fmaf(hv.x, w.x, acc[j]))));
            }
        }
        #pragma unroll
        for (int j = 0; j < KNN; ++j) part[((t >> 6) * KNN + j) * DH + (t & 63)] = acc[j];
        __syncthreads();
        for (int r = 0; r < 4; ++r) {
            int v = r * 256 + t; int j = v >> 6; int dd = v & 63;
            sims[v] = part[j * DH + dd] + part[(KNN + j) * DH + dd]
                    + part[(2 * KNN + j) * DH + dd] + part[(3 * KNN + j) * DH + dd] + ab2s[dd];
        }
        __syncthreads();
        // softmax over j for each d
        if (t < DH) {
            float m = -__builtin_inff();
            #pragma unroll
            for (int j = 0; j < KNN; ++j) m = fmaxf(m, sims[j * DH + t]);
            float ex[KNN]; float sum = 0.0f;
            #pragma unroll
            for (int j = 0; j < KNN; ++j) { ex[j] = __expf(sims[j * DH + t] - m); sum += ex[j]; }
            float inv = 1.0f / sum;
            float* ao = attn + (((size_t)(b * HH + h) * NPT + i) * KNN) * DH + t;
            #pragma unroll
            for (int j = 0; j < KNN; ++j) ao[j * DH] = ex[j] * inv;
        }
        __syncthreads();
    }
}

// ---- K4a: partial sums of attn^2 over i (128-chunk per block) -> npart
__global__ __launch_bounds__(256) void k_norm1(const float* __restrict__ attn, float* __restrict__ npart)
{
    const int j = blockIdx.x, h = blockIdx.y, bz = blockIdx.z;
    const int b = bz >> 3, ic = bz & 7;
    const int t = threadIdx.x, d = t & 63, q4 = t >> 6;
    const float* base = attn + ((size_t)(b * HH + h) * NPT) * KNN * DH + j * DH + d;
    float acc = 0.0f;
    for (int r = 0; r < 32; ++r) {
        int i = ic * 128 + q4 + r * 4;
        float a = base[(size_t)i * KNN * DH];
        acc = fmaf(a, a, acc);
    }
    __shared__ float red[256];
    red[t] = acc;
    __syncthreads();
    if (q4 == 0) {
        float s = red[d] + red[64 + d] + red[128 + d] + red[192 + d];
        npart[(((size_t)(b * HH + h) * KNN + j) * DH + d) + 16384 * ic] = s;
    }
}

// ---- K4b: reduce partials -> norm = sqrt(sum_i attn^2), (b,h,j,d)
__global__ __launch_bounds__(256) void k_norm2(const float* __restrict__ npart, float* __restrict__ nrm)
{
    int v = blockIdx.x * 256 + threadIdx.x;
    float s = 0.0f;
    #pragma unroll
    for (int ic = 0; ic < 8; ++ic) s += npart[v + 16384 * ic];
    nrm[v] = sqrtf(s);
}

// ---- K5: agg[b,h,i,d] = sum_j attn/max(norm,1e-12) * (V[gather] + rpe_h)
// Block = (it in [0,256), h, b); i = it*4 + (t>>6), d = t&63.
__global__ __launch_bounds__(256) void k_agg(const float* __restrict__ attn,
                                             const float* __restrict__ nrm,
                                             const float* __restrict__ Vws,
                                             const float* __restrict__ canonical,
                                             const int* __restrict__ nbr,
                                             const float* __restrict__ pw1,
                                             const float* __restrict__ pb1,
                                             const float* __restrict__ pw2,
                                             const float* __restrict__ pb2,
                                             float* __restrict__ agg)
{
    const int it = blockIdx.x, h = blockIdx.y, b = blockIdx.z, t = threadIdx.x;
    const int d = t & 63, si = t >> 6;
    const int i = it * 4 + si;
    __shared__ float rn[KNN * DH];        // 4 KB
    __shared__ float w2h[POSH * DH];      // 16 KB
    __shared__ float h1[4][KNN * POSH];   // 16 KB
    __shared__ float pw1s[3 * POSH];
    __shared__ float pb1s[POSH];
    __shared__ float pb2h[DH];
    __shared__ float rel[4][KNN][3];
    __shared__ int nbrD[4][KNN];

    for (int v = t; v < KNN * DH; v += 256)
        rn[v] = 1.0f / fmaxf(nrm[((size_t)(b * HH + h) * KNN) * DH + v], 1e-12f);
    for (int v = t; v < POSH * DH; v += 256)
        w2h[v] = pw2[(size_t)(v >> 6) * INNER + h * DH + (v & 63)];
    if (t < 192) pw1s[t] = pw1[t];
    if (t < 64) { pb1s[t] = pb1[t]; pb2h[t] = pb2[h * DH + t]; }
    if (t < 64) {
        int si2 = t >> 4, jj = t & 15;
        int i2 = it * 4 + si2;
        int nv2 = nbr[((size_t)b * NPT + i2) * KNN + jj];
        const float* cn = canonical + ((size_t)b * NPT + nv2) * 3;
        const float* ci = canonical + ((size_t)b * NPT + i2) * 3;
        rel[si2][jj][0] = cn[0] - ci[0];
        rel[si2][jj][1] = cn[1] - ci[1];
        rel[si2][jj][2] = cn[2] - ci[2];
        nbrD[si2][jj] = nbr[((size_t)b * NPT + h * 128 + (i2 >> 3)) * KNN + jj];
    }
    __syncthreads();
    for (int r = 0; r < 16; ++r) {
        int v = r * 256 + t; int si2 = v >> 10; int j = (v >> 6) & 15; int p = v & 63;
        float a = pb1s[p];
        a = fmaf(rel[si2][j][0], pw1s[p], a);
        a = fmaf(rel[si2][j][1], pw1s[64 + p], a);
        a = fmaf(rel[si2][j][2], pw1s[128 + p], a);
        h1[si2][j * POSH + p] = fmaxf(a, 0.0f);
    }
    __syncthreads();

    float acc = 0.0f;
    const float* ab = attn + (((size_t)(b * HH + h) * NPT + i) * KNN) * DH + d;
    for (int j = 0; j < KNN; ++j) {
        int nv = nbrD[si][2 * (i & 7) + (j >> 3)];
        float a = ab[j * DH];
        float vv = Vws[(((size_t)b * HH + (nv >> 7)) * NPT + (nv & 127) * 8 + (j & 7)) * DH + d];
        float rp = pb2h[d];
        #pragma unroll
        for (int p = 0; p < POSH; ++p) rp = fmaf(h1[si][j * POSH + p], w2h[p * DH + d], rp);
        acc = fmaf(a * rn[j * DH + d], vv + rp, acc);
    }
    agg[((size_t)b * NPT + i) * INNER + h * DH + d] = acc;
}

// ---- K6: out = agg @ w_out + b_out, f32 output
__global__ __launch_bounds__(256) void k_out(const float* __restrict__ agg,
                                             const float* __restrict__ wout,
                                             const float* __restrict__ bout,
                                             float* __restrict__ outp)
{
    __shared__ float as[8][INNER];
    const int t = threadIdx.x;
    const int g0 = blockIdx.x * 8;
    for (int v = t; v < 8 * 128; v += 256) {
        int r = v >> 7, c4 = v & 127;
        ((float4*)as[r])[c4] = ((const float4*)(agg + (size_t)(g0 + r) * INNER))[c4];
    }
    __syncthreads();
    float2 bb = ((const float2*)bout)[t];
    float a0[8], a1[8];
    #pragma unroll
    for (int r = 0; r < 8; ++r) { a0[r] = bb.x; a1[r] = bb.y; }
    for (int e = 0; e < INNER; ++e) {
        float2 w = ((const float2*)(wout + (size_t)e * EMB))[t];
        #pragma unroll
        for (int r = 0; r < 8; ++r) {
            float a = as[r][e];
            a0[r] = fmaf(a, w.x, a0[r]);
            a1[r] = fmaf(a, w.y, a1[r]);
        }
    }
    #pragma unroll
    for (int r = 0; r < 8; ++r)
        ((float2*)(outp + (size_t)(g0 + r) * EMB))[t] = make_float2(a0[r], a1[r]);
}

extern "C" void kernel_launch(void* const* d_in, const int* in_sizes, int n_in,
                              void* d_out, int out_size, void* d_ws, size_t ws_size,
                              hipStream_t stream) {
    const float* query     = (const float*)d_in[0];
    const float* key_in    = (const float*)d_in[1];
    const float* value     = (const float*)d_in[2];
    const float* canonical = (const float*)d_in[3];
    const float* wq   = (const float*)d_in[4];
    const float* wk   = (const float*)d_in[5];
    const float* wv   = (const float*)d_in[6];
    const float* wout = (const float*)d_in[7];
    const float* bout = (const float*)d_in[8];
    const float* pw1  = (const float*)d_in[9];
    const float* pb1  = (const float*)d_in[10];
    const float* pw2  = (const float*)d_in[11];
    const float* pb2  = (const float*)d_in[12];
    const float* aw1  = (const float*)d_in[13];
    const float* ab1  = (const float*)d_in[14];
    const float* aw2  = (const float*)d_in[15];
    const float* ab2  = (const float*)d_in[16];

    float* ws    = (float*)d_ws;
    float* Dws   = ws;                    // 1,048,576
    float* Vws   = ws + 1048576;          // 1,048,576
    float* aggb  = ws + 2097152;          // 1,048,576
    float* nrm   = ws + 3145728;          // 16,384
    float* npart = ws + 3162112;          // 131,072
    int*   nbr   = (int*)(ws + 3293184);  // 32,768 ints
    float* attn  = ws + 3325952;          // 16,777,216  (end 20,103,168 floats ~80.4MB)

    k_proj<<<256, 256, 0, stream>>>(query, key_in, value, wq, wk, wv, Dws, Vws);
    k_knn<<<dim3(NPT, BS), 256, 0, stream>>>(canonical, nbr);
    k_attn<<<dim3(128, HH, BS), 256, 0, stream>>>(Dws, canonical, nbr, pw1, pb1, pw2, pb2,
                                                  aw1, ab1, aw2, ab2, attn);
    k_norm1<<<dim3(KNN, HH, BS * 8), 256, 0, stream>>>(attn, npart);
    k_norm2<<<64, 256, 0, stream>>>(npart, nrm);
    k_agg<<<dim3(256, HH, BS), 256, 0, stream>>>(attn, nrm, Vws, canonical, nbr,
                                                 pw1, pb1, pw2, pb2, aggb);
    k_out<<<256, 256, 0, stream>>>(aggb, wout, bout, (float*)d_out);
}

// Round 3
// 461.364 us; speedup vs baseline: 2.0189x; 2.0189x over previous
//
#include <hip/hip_runtime.h>

// MultiHeadVectorAttention — round 3: MFMA (split-bf16) attn-MLP + rpe in k_attn.
// bs=2, n=1024, H=8, DH=64, K=16, EMB=INNER=512, AINNER=256, POSH=64.
// Workspace (floats): D(1M) V(1M) agg(1M) nrm(16K) npart(128K) nbr(32K int) attn(16.7M) ~= 80.4 MB.

#define BS 2
#define NPT 1024
#define HH 8
#define DH 64
#define KNN 16
#define EMB 512
#define INNER 512
#define AINNER 256
#define POSH 64

typedef unsigned short u16;
typedef unsigned int u32;
typedef __attribute__((ext_vector_type(8))) short bf16x8;
typedef __attribute__((ext_vector_type(4))) float f32x4;

__device__ __forceinline__ float bf2f(u16 b) { union { u32 u; float f; } v; v.u = ((u32)b) << 16; return v.f; }
__device__ __forceinline__ u16 f2bf(float f) {
    u32 x = __float_as_uint(f);
    u32 r = x + 0x7fffu + ((x >> 16) & 1u);
    return (u16)(r >> 16);
}

// ---- K1: projections. D = query@wq - key@wk, V = value@wv, stored (b,h,i,d) f32.
__global__ __launch_bounds__(256) void k_proj(const float* __restrict__ query,
                                              const float* __restrict__ key_in,
                                              const float* __restrict__ value,
                                              const float* __restrict__ wq,
                                              const float* __restrict__ wk,
                                              const float* __restrict__ wv,
                                              float* __restrict__ Dws,
                                              float* __restrict__ Vws)
{
    __shared__ float qs[8][EMB], ks[8][EMB], vs[8][EMB];
    const int t = threadIdx.x;
    const int g0 = blockIdx.x * 8;
    for (int v = t; v < 8 * 128; v += 256) {
        int r = v >> 7, c4 = v & 127;
        ((float4*)qs[r])[c4] = ((const float4*)(query  + (size_t)(g0 + r) * EMB))[c4];
        ((float4*)ks[r])[c4] = ((const float4*)(key_in + (size_t)(g0 + r) * EMB))[c4];
        ((float4*)vs[r])[c4] = ((const float4*)(value  + (size_t)(g0 + r) * EMB))[c4];
    }
    __syncthreads();
    float aD0[8] = {}, aD1[8] = {}, aV0[8] = {}, aV1[8] = {};
    for (int e = 0; e < EMB; ++e) {
        float2 wqe = ((const float2*)(wq + (size_t)e * INNER))[t];
        float2 wke = ((const float2*)(wk + (size_t)e * INNER))[t];
        float2 wve = ((const float2*)(wv + (size_t)e * INNER))[t];
        #pragma unroll
        for (int r = 0; r < 8; ++r) {
            float qe = qs[r][e], ke = ks[r][e], ve = vs[r][e];
            aD0[r] = fmaf(qe, wqe.x, aD0[r]); aD0[r] = fmaf(-ke, wke.x, aD0[r]);
            aD1[r] = fmaf(qe, wqe.y, aD1[r]); aD1[r] = fmaf(-ke, wke.y, aD1[r]);
            aV0[r] = fmaf(ve, wve.x, aV0[r]);
            aV1[r] = fmaf(ve, wve.y, aV1[r]);
        }
    }
    const int c0 = 2 * t;
    const int h = c0 >> 6, d0 = c0 & 63;
    #pragma unroll
    for (int r = 0; r < 8; ++r) {
        int g = g0 + r;
        int b = g >> 10, i = g & 1023;
        size_t off = (((size_t)(b * HH + h)) * NPT + i) * DH + d0;
        *(float2*)&Dws[off] = make_float2(aD0[r], aD1[r]);
        *(float2*)&Vws[off] = make_float2(aV0[r], aV1[r]);
    }
}

// ---- K2: KNN, 16 smallest d2 per (b,i), ties -> lowest index (stable top_k).
__global__ __launch_bounds__(256) void k_knn(const float* __restrict__ canonical, int* __restrict__ nbr)
{
    const int i = blockIdx.x, b = blockIdx.y, t = threadIdx.x;
    __shared__ float d2[NPT];
    __shared__ float redv[256];
    __shared__ int   redi[256];
    const float* cb = canonical + (size_t)b * NPT * 3;
    const float xi = cb[i*3+0], yi = cb[i*3+1], zi = cb[i*3+2];
    for (int j = t; j < NPT; j += 256) {
        float dx = __fsub_rn(cb[j*3+0], xi);
        float dy = __fsub_rn(cb[j*3+1], yi);
        float dz = __fsub_rn(cb[j*3+2], zi);
        d2[j] = __fadd_rn(__fadd_rn(__fmul_rn(dx,dx), __fmul_rn(dy,dy)), __fmul_rn(dz,dz));
    }
    __syncthreads();
    for (int sel = 0; sel < KNN; ++sel) {
        float bv = __builtin_inff(); int bi = NPT;
        for (int j = t; j < NPT; j += 256) {
            float v = d2[j];
            if (v < bv) { bv = v; bi = j; }
        }
        redv[t] = bv; redi[t] = bi;
        __syncthreads();
        for (int s = 128; s > 0; s >>= 1) {
            if (t < s) {
                float v2 = redv[t+s]; int i2 = redi[t+s];
                float v1 = redv[t];   int i1 = redi[t];
                if (v2 < v1 || (v2 == v1 && i2 < i1)) { redv[t] = v2; redi[t] = i2; }
            }
            __syncthreads();
        }
        if (t == 0) { nbr[((size_t)b*NPT + i)*KNN + sel] = redi[0]; d2[redi[0]] = __builtin_inff(); }
        __syncthreads();
    }
}

// ---- K3: MFMA attn kernel. Block = (it, h, b); 4 waves cooperate per i.
// rpe (M16,N64,K64), MLP1 (M16,N256,K64), MLP2 (M16,N64,K256), all split-bf16 MFMA.
__global__ __launch_bounds__(256) void k_attn(const float* __restrict__ Dws,
                                              const float* __restrict__ canonical,
                                              const int* __restrict__ nbr,
                                              const float* __restrict__ pw1,
                                              const float* __restrict__ pb1,
                                              const float* __restrict__ pw2,
                                              const float* __restrict__ pb2,
                                              const float* __restrict__ aw1,
                                              const float* __restrict__ ab1,
                                              const float* __restrict__ aw2,
                                              const float* __restrict__ ab2,
                                              float* __restrict__ attn)
{
    const int it = blockIdx.x, h = blockIdx.y, b = blockIdx.z, t = threadIdx.x;
    const int l = t & 63, w = t >> 6;
    const int lm = l & 15, lg = (l >> 4) * 8;   // frag row/col, k-subchunk offset

    __shared__ u16 rw2hi[64 * 72], rw2lo[64 * 72];   // pos_w2 head-slice, transposed [d][p], split
    __shared__ u16 h1hi[16 * 72],  h1lo[16 * 72];    // relu(rel@pw1+pb1) split
    __shared__ u16 Xhi[16 * 72],   Xlo[16 * 72];     // x = D_gather + rpe, split
    __shared__ u16 Hhi[16 * 264],  Hlo[16 * 264];    // relu(MLP1) split
    __shared__ float sims[16 * 68];
    __shared__ float pw1s[3 * POSH];
    __shared__ float pb1s[POSH];
    __shared__ float pb2h[DH];
    __shared__ float rel_all[8][KNN][3];
    __shared__ int nbrrow[KNN];

    // ---- per-wave register weight fragments (aw1, aw2 split to hi/lo bf16)
    bf16x8 w1fh[8], w1fl[8];   // [q*2+kc]: e = (w*4+q)*16+lm, d = kc*32+lg+r
    bf16x8 w2fh[8], w2fl[8];   // [kc]:     d = w*16+lm,       e = kc*32+lg+r
    float b1v[4];
    #pragma unroll
    for (int q = 0; q < 4; ++q) {
        int e = (w * 4 + q) * 16 + lm;
        const float* src = aw1 + ((size_t)h * AINNER + e) * DH;
        b1v[q] = ab1[h * AINNER + e];
        #pragma unroll
        for (int kc = 0; kc < 2; ++kc) {
            int d0 = kc * 32 + lg;
            #pragma unroll
            for (int r = 0; r < 8; ++r) {
                float f = src[d0 + r];
                u16 hi = f2bf(f);
                w1fh[q*2+kc][r] = (short)hi;
                w1fl[q*2+kc][r] = (short)f2bf(f - bf2f(hi));
            }
        }
    }
    const int dd = w * 16 + lm;
    const float b2v = ab2[h * DH + dd];
    {
        const float* src = aw2 + ((size_t)h * DH + dd) * AINNER;
        #pragma unroll
        for (int kc = 0; kc < 8; ++kc) {
            int e0 = kc * 32 + lg;
            #pragma unroll
            for (int r = 0; r < 8; ++r) {
                float f = src[e0 + r];
                u16 hi = f2bf(f);
                w2fh[kc][r] = (short)hi;
                w2fl[kc][r] = (short)f2bf(f - bf2f(hi));
            }
        }
    }

    // ---- LDS preamble
    for (int v = t; v < 64 * 64; v += 256) {
        int p = v & 63, d = v >> 6;
        float f = pw2[(size_t)p * INNER + h * DH + d];
        u16 hi = f2bf(f);
        rw2hi[d * 72 + p] = hi;
        rw2lo[d * 72 + p] = f2bf(f - bf2f(hi));
    }
    if (t < 192) pw1s[t] = pw1[t];
    if (t < 64) { pb1s[t] = pb1[t]; pb2h[t] = pb2[h * DH + t]; }
    if (t < KNN) nbrrow[t] = nbr[((size_t)b * NPT + h * 128 + it) * KNN + t];
    if (t < 128) {
        int ti = t >> 4, jj = t & 15;
        int i2 = it * 8 + ti;
        int nv2 = nbr[((size_t)b * NPT + i2) * KNN + jj];
        const float* cn = canonical + ((size_t)b * NPT + nv2) * 3;
        const float* ci = canonical + ((size_t)b * NPT + i2) * 3;
        rel_all[ti][jj][0] = cn[0] - ci[0];
        rel_all[ti][jj][1] = cn[1] - ci[1];
        rel_all[ti][jj][2] = cn[2] - ci[2];
    }
    __syncthreads();

    for (int ti = 0; ti < 8; ++ti) {
        const int i = it * 8 + ti;
        // ---- h1 = relu(rel@pw1 + pb1), split to bf16 hi/lo
        #pragma unroll
        for (int r = 0; r < 4; ++r) {
            int v = r * 256 + t; int j = v >> 6; int p = v & 63;
            float a = pb1s[p];
            a = fmaf(rel_all[ti][j][0], pw1s[p], a);
            a = fmaf(rel_all[ti][j][1], pw1s[64 + p], a);
            a = fmaf(rel_all[ti][j][2], pw1s[128 + p], a);
            a = fmaxf(a, 0.0f);
            u16 hi = f2bf(a);
            h1hi[j * 72 + p] = hi;
            h1lo[j * 72 + p] = f2bf(a - bf2f(hi));
        }
        __syncthreads();
        // ---- rpe MFMA (wave w owns d-tile w) + gather + X split-write
        {
            f32x4 racc = {0.f, 0.f, 0.f, 0.f};
            #pragma unroll
            for (int kc = 0; kc < 2; ++kc) {
                bf16x8 ah = *(const bf16x8*)&h1hi[lm * 72 + kc * 32 + lg];
                bf16x8 al = *(const bf16x8*)&h1lo[lm * 72 + kc * 32 + lg];
                bf16x8 bh = *(const bf16x8*)&rw2hi[dd * 72 + kc * 32 + lg];
                bf16x8 bl = *(const bf16x8*)&rw2lo[dd * 72 + kc * 32 + lg];
                racc = __builtin_amdgcn_mfma_f32_16x16x32_bf16(ah, bh, racc, 0, 0, 0);
                racc = __builtin_amdgcn_mfma_f32_16x16x32_bf16(al, bh, racc, 0, 0, 0);
                racc = __builtin_amdgcn_mfma_f32_16x16x32_bf16(ah, bl, racc, 0, 0, 0);
            }
            float pb2v = pb2h[dd];
            #pragma unroll
            for (int r = 0; r < 4; ++r) {
                int j = (l >> 4) * 4 + r;
                int nv = nbrrow[2 * ti + (j >> 3)];
                float dv = Dws[(((size_t)b * HH + (nv >> 7)) * NPT + (nv & 127) * 8 + (j & 7)) * DH + dd];
                float x = dv + (racc[r] + pb2v);
                u16 hi = f2bf(x);
                Xhi[j * 72 + dd] = hi;
                Xlo[j * 72 + dd] = f2bf(x - bf2f(hi));
            }
        }
        __syncthreads();
        // ---- MLP1: H = relu(X @ W1^T + b1), wave w owns e-tiles 4w..4w+3
        {
            f32x4 acc1[4] = {{0,0,0,0},{0,0,0,0},{0,0,0,0},{0,0,0,0}};
            #pragma unroll
            for (int kc = 0; kc < 2; ++kc) {
                bf16x8 ah = *(const bf16x8*)&Xhi[lm * 72 + kc * 32 + lg];
                bf16x8 al = *(const bf16x8*)&Xlo[lm * 72 + kc * 32 + lg];
                #pragma unroll
                for (int q = 0; q < 4; ++q) {
                    int fi = q * 2 + kc;
                    acc1[q] = __builtin_amdgcn_mfma_f32_16x16x32_bf16(ah, w1fh[fi], acc1[q], 0, 0, 0);
                    acc1[q] = __builtin_amdgcn_mfma_f32_16x16x32_bf16(al, w1fh[fi], acc1[q], 0, 0, 0);
                    acc1[q] = __builtin_amdgcn_mfma_f32_16x16x32_bf16(ah, w1fl[fi], acc1[q], 0, 0, 0);
                }
            }
            #pragma unroll
            for (int q = 0; q < 4; ++q) {
                int ee = (w * 4 + q) * 16 + lm;
                #pragma unroll
                for (int r = 0; r < 4; ++r) {
                    int jj = (l >> 4) * 4 + r;
                    float v2 = fmaxf(acc1[q][r] + b1v[q], 0.0f);
                    u16 hi = f2bf(v2);
                    Hhi[jj * 264 + ee] = hi;
                    Hlo[jj * 264 + ee] = f2bf(v2 - bf2f(hi));
                }
            }
        }
        __syncthreads();
        // ---- MLP2: sim = H @ W2^T + b2, wave w owns d-tile w; 4 interleaved partial accs
        {
            f32x4 acc2[4] = {{0,0,0,0},{0,0,0,0},{0,0,0,0},{0,0,0,0}};
            #pragma unroll
            for (int kc = 0; kc < 8; ++kc) {
                bf16x8 ah = *(const bf16x8*)&Hhi[lm * 264 + kc * 32 + lg];
                bf16x8 al = *(const bf16x8*)&Hlo[lm * 264 + kc * 32 + lg];
                int p = kc & 3;
                acc2[p] = __builtin_amdgcn_mfma_f32_16x16x32_bf16(ah, w2fh[kc], acc2[p], 0, 0, 0);
                acc2[p] = __builtin_amdgcn_mfma_f32_16x16x32_bf16(al, w2fh[kc], acc2[p], 0, 0, 0);
                acc2[p] = __builtin_amdgcn_mfma_f32_16x16x32_bf16(ah, w2fl[kc], acc2[p], 0, 0, 0);
            }
            #pragma unroll
            for (int r = 0; r < 4; ++r) {
                float s = ((acc2[0][r] + acc2[1][r]) + (acc2[2][r] + acc2[3][r])) + b2v;
                sims[((l >> 4) * 4 + r) * 68 + dd] = s;
            }
        }
        __syncthreads();
        // ---- softmax over j for each d
        if (t < DH) {
            float m = -__builtin_inff();
            #pragma unroll
            for (int j = 0; j < KNN; ++j) m = fmaxf(m, sims[j * 68 + t]);
            float ex[KNN]; float sum = 0.0f;
            #pragma unroll
            for (int j = 0; j < KNN; ++j) { ex[j] = __expf(sims[j * 68 + t] - m); sum += ex[j]; }
            float inv = 1.0f / sum;
            float* ao = attn + (((size_t)(b * HH + h) * NPT + i) * KNN) * DH + t;
            #pragma unroll
            for (int j = 0; j < KNN; ++j) ao[j * DH] = ex[j] * inv;
        }
        __syncthreads();
    }
}

// ---- K4a: partial sums of attn^2 over i (128-chunk per block) -> npart
__global__ __launch_bounds__(256) void k_norm1(const float* __restrict__ attn, float* __restrict__ npart)
{
    const int j = blockIdx.x, h = blockIdx.y, bz = blockIdx.z;
    const int b = bz >> 3, ic = bz & 7;
    const int t = threadIdx.x, d = t & 63, q4 = t >> 6;
    const float* base = attn + ((size_t)(b * HH + h) * NPT) * KNN * DH + j * DH + d;
    float acc = 0.0f;
    for (int r = 0; r < 32; ++r) {
        int i = ic * 128 + q4 + r * 4;
        float a = base[(size_t)i * KNN * DH];
        acc = fmaf(a, a, acc);
    }
    __shared__ float red[256];
    red[t] = acc;
    __syncthreads();
    if (q4 == 0) {
        float s = red[d] + red[64 + d] + red[128 + d] + red[192 + d];
        npart[(((size_t)(b * HH + h) * KNN + j) * DH + d) + 16384 * ic] = s;
    }
}

// ---- K4b: reduce partials -> norm = sqrt(sum_i attn^2), (b,h,j,d)
__global__ __launch_bounds__(256) void k_norm2(const float* __restrict__ npart, float* __restrict__ nrm)
{
    int v = blockIdx.x * 256 + threadIdx.x;
    float s = 0.0f;
    #pragma unroll
    for (int ic = 0; ic < 8; ++ic) s += npart[v + 16384 * ic];
    nrm[v] = sqrtf(s);
}

// ---- K5: agg[b,h,i,d] = sum_j attn/max(norm,1e-12) * (V[gather] + rpe_h)
__global__ __launch_bounds__(256) void k_agg(const float* __restrict__ attn,
                                             const float* __restrict__ nrm,
                                             const float* __restrict__ Vws,
                                             const float* __restrict__ canonical,
                                             const int* __restrict__ nbr,
                                             const float* __restrict__ pw1,
                                             const float* __restrict__ pb1,
                                             const float* __restrict__ pw2,
                                             const float* __restrict__ pb2,
                                             float* __restrict__ agg)
{
    const int it = blockIdx.x, h = blockIdx.y, b = blockIdx.z, t = threadIdx.x;
    const int d = t & 63, si = t >> 6;
    const int i = it * 4 + si;
    __shared__ float rn[KNN * DH];
    __shared__ float w2h[POSH * DH];
    __shared__ float h1[4][KNN * POSH];
    __shared__ float pw1s[3 * POSH];
    __shared__ float pb1s[POSH];
    __shared__ float pb2h[DH];
    __shared__ float rel[4][KNN][3];
    __shared__ int nbrD[4][KNN];

    for (int v = t; v < KNN * DH; v += 256)
        rn[v] = 1.0f / fmaxf(nrm[((size_t)(b * HH + h) * KNN) * DH + v], 1e-12f);
    for (int v = t; v < POSH * DH; v += 256)
        w2h[v] = pw2[(size_t)(v >> 6) * INNER + h * DH + (v & 63)];
    if (t < 192) pw1s[t] = pw1[t];
    if (t < 64) { pb1s[t] = pb1[t]; pb2h[t] = pb2[h * DH + t]; }
    if (t < 64) {
        int si2 = t >> 4, jj = t & 15;
        int i2 = it * 4 + si2;
        int nv2 = nbr[((size_t)b * NPT + i2) * KNN + jj];
        const float* cn = canonical + ((size_t)b * NPT + nv2) * 3;
        const float* ci = canonical + ((size_t)b * NPT + i2) * 3;
        rel[si2][jj][0] = cn[0] - ci[0];
        rel[si2][jj][1] = cn[1] - ci[1];
        rel[si2][jj][2] = cn[2] - ci[2];
        nbrD[si2][jj] = nbr[((size_t)b * NPT + h * 128 + (i2 >> 3)) * KNN + jj];
    }
    __syncthreads();
    for (int r = 0; r < 16; ++r) {
        int v = r * 256 + t; int si2 = v >> 10; int j = (v >> 6) & 15; int p = v & 63;
        float a = pb1s[p];
        a = fmaf(rel[si2][j][0], pw1s[p], a);
        a = fmaf(rel[si2][j][1], pw1s[64 + p], a);
        a = fmaf(rel[si2][j][2], pw1s[128 + p], a);
        h1[si2][j * POSH + p] = fmaxf(a, 0.0f);
    }
    __syncthreads();

    float acc = 0.0f;
    const float* ab = attn + (((size_t)(b * HH + h) * NPT + i) * KNN) * DH + d;
    for (int j = 0; j < KNN; ++j) {
        int nv = nbrD[si][2 * (i & 7) + (j >> 3)];
        float a = ab[j * DH];
        float vv = Vws[(((size_t)b * HH + (nv >> 7)) * NPT + (nv & 127) * 8 + (j & 7)) * DH + d];
        float rp = pb2h[d];
        #pragma unroll
        for (int p = 0; p < POSH; ++p) rp = fmaf(h1[si][j * POSH + p], w2h[p * DH + d], rp);
        acc = fmaf(a * rn[j * DH + d], vv + rp, acc);
    }
    agg[((size_t)b * NPT + i) * INNER + h * DH + d] = acc;
}

// ---- K6: out = agg @ w_out + b_out, f32 output
__global__ __launch_bounds__(256) void k_out(const float* __restrict__ agg,
                                             const float* __restrict__ wout,
                                             const float* __restrict__ bout,
                                             float* __restrict__ outp)
{
    __shared__ float as[8][INNER];
    const int t = threadIdx.x;
    const int g0 = blockIdx.x * 8;
    for (int v = t; v < 8 * 128; v += 256) {
        int r = v >> 7, c4 = v & 127;
        ((float4*)as[r])[c4] = ((const float4*)(agg + (size_t)(g0 + r) * INNER))[c4];
    }
    __syncthreads();
    float2 bb = ((const float2*)bout)[t];
    float a0[8], a1[8];
    #pragma unroll
    for (int r = 0; r < 8; ++r) { a0[r] = bb.x; a1[r] = bb.y; }
    for (int e = 0; e < INNER; ++e) {
        float2 w = ((const float2*)(wout + (size_t)e * EMB))[t];
        #pragma unroll
        for (int r = 0; r < 8; ++r) {
            float a = as[r][e];
            a0[r] = fmaf(a, w.x, a0[r]);
            a1[r] = fmaf(a, w.y, a1[r]);
        }
    }
    #pragma unroll
    for (int r = 0; r < 8; ++r)
        ((float2*)(outp + (size_t)(g0 + r) * EMB))[t] = make_float2(a0[r], a1[r]);
}

extern "C" void kernel_launch(void* const* d_in, const int* in_sizes, int n_in,
                              void* d_out, int out_size, void* d_ws, size_t ws_size,
                              hipStream_t stream) {
    const float* query     = (const float*)d_in[0];
    const float* key_in    = (const float*)d_in[1];
    const float* value     = (const float*)d_in[2];
    const float* canonical = (const float*)d_in[3];
    const float* wq   = (const float*)d_in[4];
    const float* wk   = (const float*)d_in[5];
    const float* wv   = (const float*)d_in[6];
    const float* wout = (const float*)d_in[7];
    const float* bout = (const float*)d_in[8];
    const float* pw1  = (const float*)d_in[9];
    const float* pb1  = (const float*)d_in[10];
    const float* pw2  = (const float*)d_in[11];
    const float* pb2  = (const float*)d_in[12];
    const float* aw1  = (const float*)d_in[13];
    const float* ab1  = (const float*)d_in[14];
    const float* aw2  = (const float*)d_in[15];
    const float* ab2  = (const float*)d_in[16];

    float* ws    = (float*)d_ws;
    float* Dws   = ws;                    // 1,048,576
    float* Vws   = ws + 1048576;          // 1,048,576
    float* aggb  = ws + 2097152;          // 1,048,576
    float* nrm   = ws + 3145728;          // 16,384
    float* npart = ws + 3162112;          // 131,072
    int*   nbr   = (int*)(ws + 3293184);  // 32,768 ints
    float* attn  = ws + 3325952;          // 16,777,216

    k_proj<<<256, 256, 0, stream>>>(query, key_in, value, wq, wk, wv, Dws, Vws);
    k_knn<<<dim3(NPT, BS), 256, 0, stream>>>(canonical, nbr);
    k_attn<<<dim3(128, HH, BS), 256, 0, stream>>>(Dws, canonical, nbr, pw1, pb1, pw2, pb2,
                                                  aw1, ab1, aw2, ab2, attn);
    k_norm1<<<dim3(KNN, HH, BS * 8), 256, 0, stream>>>(attn, npart);
    k_norm2<<<64, 256, 0, stream>>>(npart, nrm);
    k_agg<<<dim3(256, HH, BS), 256, 0, stream>>>(attn, nrm, Vws, canonical, nbr,
                                                 pw1, pb1, pw2, pb2, aggb);
    k_out<<<256, 256, 0, stream>>>(aggb, wout, bout, (float*)d_out);
}

// Round 4
// 323.553 us; speedup vs baseline: 2.8789x; 1.4259x over previous
//
#include <hip/hip_runtime.h>

// MultiHeadVectorAttention — round 4: restructured MFMA k_attn (3 barriers/ti,
// in-wave softmax, trunc-split, prepped split weights), streaming k_agg, shfl k_knn.
// bs=2, n=1024, H=8, DH=64, K=16, EMB=INNER=512, AINNER=256, POSH=64.

#define BS 2
#define NPT 1024
#define HH 8
#define DH 64
#define KNN 16
#define EMB 512
#define INNER 512
#define AINNER 256
#define POSH 64

typedef unsigned short u16;
typedef unsigned int u32;
typedef __attribute__((ext_vector_type(8))) short bf16x8;
typedef __attribute__((ext_vector_type(4))) float f32x4;

__device__ __forceinline__ float bf2f(u16 b) { union { u32 u; float f; } v; v.u = ((u32)b) << 16; return v.f; }
__device__ __forceinline__ u16 f2bf_rne(float f) {
    u32 x = __float_as_uint(f);
    u32 r = x + 0x7fffu + ((x >> 16) & 1u);
    return (u16)(r >> 16);
}
// truncation split: hi = trunc-bf16(f), lo = trunc-bf16(f - hi). |err| <= 2^-16 rel.
__device__ __forceinline__ void split2(float f, u16& hi, u16& lo) {
    u32 bits = __float_as_uint(f);
    hi = (u16)(bits >> 16);
    float resid = f - __uint_as_float(bits & 0xffff0000u);
    lo = (u16)(__float_as_uint(resid) >> 16);
}

// ---- K0: pre-split weights into bf16 hi/lo planes.
// v in [0,131072): w1 planes from aw1 (h,e,d) linear.
// v in [131072,262144): w2 planes from aw2 (h,d,e) linear.
// v in [262144,294912): rw2 planes: rw2[h][d][p] = pw2[p][h*64+d].
__global__ __launch_bounds__(256) void k_prep(const float* __restrict__ aw1,
                                              const float* __restrict__ aw2,
                                              const float* __restrict__ pw2,
                                              u16* __restrict__ w1hi, u16* __restrict__ w1lo,
                                              u16* __restrict__ w2hi, u16* __restrict__ w2lo,
                                              u16* __restrict__ rw2hi, u16* __restrict__ rw2lo)
{
    int v = blockIdx.x * 256 + threadIdx.x;
    float f; u16* dhi; u16* dlo; int idx;
    if (v < 131072) { f = aw1[v]; dhi = w1hi; dlo = w1lo; idx = v; }
    else if (v < 262144) { idx = v - 131072; f = aw2[idx]; dhi = w2hi; dlo = w2lo; }
    else {
        idx = v - 262144;                    // idx = (h*64+d)*64 + p
        int p = idx & 63; int hd = idx >> 6;
        int h = hd >> 6;  int d = hd & 63;
        f = pw2[(size_t)p * INNER + h * DH + d];
        dhi = rw2hi; dlo = rw2lo;
    }
    u16 hi, lo; split2(f, hi, lo);
    dhi[idx] = hi; dlo[idx] = lo;
}

// ---- K1: projections. D = query@wq - key@wk, V = value@wv, stored (b,h,i,d) f32.
__global__ __launch_bounds__(256) void k_proj(const float* __restrict__ query,
                                              const float* __restrict__ key_in,
                                              const float* __restrict__ value,
                                              const float* __restrict__ wq,
                                              const float* __restrict__ wk,
                                              const float* __restrict__ wv,
                                              float* __restrict__ Dws,
                                              float* __restrict__ Vws)
{
    __shared__ float qs[8][EMB], ks[8][EMB], vs[8][EMB];
    const int t = threadIdx.x;
    const int g0 = blockIdx.x * 8;
    for (int v = t; v < 8 * 128; v += 256) {
        int r = v >> 7, c4 = v & 127;
        ((float4*)qs[r])[c4] = ((const float4*)(query  + (size_t)(g0 + r) * EMB))[c4];
        ((float4*)ks[r])[c4] = ((const float4*)(key_in + (size_t)(g0 + r) * EMB))[c4];
        ((float4*)vs[r])[c4] = ((const float4*)(value  + (size_t)(g0 + r) * EMB))[c4];
    }
    __syncthreads();
    float aD0[8] = {}, aD1[8] = {}, aV0[8] = {}, aV1[8] = {};
    for (int e = 0; e < EMB; ++e) {
        float2 wqe = ((const float2*)(wq + (size_t)e * INNER))[t];
        float2 wke = ((const float2*)(wk + (size_t)e * INNER))[t];
        float2 wve = ((const float2*)(wv + (size_t)e * INNER))[t];
        #pragma unroll
        for (int r = 0; r < 8; ++r) {
            float qe = qs[r][e], ke = ks[r][e], ve = vs[r][e];
            aD0[r] = fmaf(qe, wqe.x, aD0[r]); aD0[r] = fmaf(-ke, wke.x, aD0[r]);
            aD1[r] = fmaf(qe, wqe.y, aD1[r]); aD1[r] = fmaf(-ke, wke.y, aD1[r]);
            aV0[r] = fmaf(ve, wve.x, aV0[r]);
            aV1[r] = fmaf(ve, wve.y, aV1[r]);
        }
    }
    const int c0 = 2 * t;
    const int h = c0 >> 6, d0 = c0 & 63;
    #pragma unroll
    for (int r = 0; r < 8; ++r) {
        int g = g0 + r;
        int b = g >> 10, i = g & 1023;
        size_t off = (((size_t)(b * HH + h)) * NPT + i) * DH + d0;
        *(float2*)&Dws[off] = make_float2(aD0[r], aD1[r]);
        *(float2*)&Vws[off] = make_float2(aV0[r], aV1[r]);
    }
}

// ---- K2: KNN, 16 smallest d2 per (b,i), ties -> lowest index (stable top_k).
__global__ __launch_bounds__(256) void k_knn(const float* __restrict__ canonical, int* __restrict__ nbr)
{
    const int i = blockIdx.x, b = blockIdx.y, t = threadIdx.x;
    const int l = t & 63, w = t >> 6;
    __shared__ float d2[NPT];
    __shared__ float wv4[4];
    __shared__ int   wi4[4];
    const float* cb = canonical + (size_t)b * NPT * 3;
    const float xi = cb[i*3+0], yi = cb[i*3+1], zi = cb[i*3+2];
    for (int j = t; j < NPT; j += 256) {
        float dx = __fsub_rn(cb[j*3+0], xi);
        float dy = __fsub_rn(cb[j*3+1], yi);
        float dz = __fsub_rn(cb[j*3+2], zi);
        d2[j] = __fadd_rn(__fadd_rn(__fmul_rn(dx,dx), __fmul_rn(dy,dy)), __fmul_rn(dz,dz));
    }
    __syncthreads();
    for (int sel = 0; sel < KNN; ++sel) {
        float bv = __builtin_inff(); int bi = NPT;
        for (int j = t; j < NPT; j += 256) {
            float v = d2[j];
            if (v < bv) { bv = v; bi = j; }   // ascending j: ties keep lowest idx
        }
        #pragma unroll
        for (int m = 32; m >= 1; m >>= 1) {
            float ov = __shfl_xor(bv, m, 64);
            int   oi = __shfl_xor(bi, m, 64);
            if (ov < bv || (ov == bv && oi < bi)) { bv = ov; bi = oi; }
        }
        if (l == 0) { wv4[w] = bv; wi4[w] = bi; }
        __syncthreads();
        if (t == 0) {
            float fv = wv4[0]; int fi = wi4[0];
            #pragma unroll
            for (int q = 1; q < 4; ++q) {
                float ov = wv4[q]; int oi = wi4[q];
                if (ov < fv || (ov == fv && oi < fi)) { fv = ov; fi = oi; }
            }
            nbr[((size_t)b*NPT + i)*KNN + sel] = fi;
            d2[fi] = __builtin_inff();
        }
        __syncthreads();
    }
}

// ---- K3: MFMA attn kernel. Block = (it, h, b); 4 waves; 3 barriers per ti.
__global__ __launch_bounds__(256) void k_attn(const float* __restrict__ Dws,
                                              const float* __restrict__ Vws,
                                              const float* __restrict__ canonical,
                                              const int* __restrict__ nbr,
                                              const float* __restrict__ pw1,
                                              const float* __restrict__ pb1,
                                              const float* __restrict__ pb2,
                                              const float* __restrict__ ab1,
                                              const float* __restrict__ ab2,
                                              const u16* __restrict__ w1hi, const u16* __restrict__ w1lo,
                                              const u16* __restrict__ w2hi, const u16* __restrict__ w2lo,
                                              const u16* __restrict__ rw2hi, const u16* __restrict__ rw2lo,
                                              u16* __restrict__ vvb,
                                              float* __restrict__ attn)
{
    const int it = blockIdx.x, h = blockIdx.y, b = blockIdx.z, t = threadIdx.x;
    const int l = t & 63, w = t >> 6;
    const int lm = l & 15, lg = (l >> 4) * 8;
    const int dd = w * 16 + lm;

    __shared__ u16 h1hi[16 * 72], h1lo[16 * 72];
    __shared__ u16 Xhi[16 * 72],  Xlo[16 * 72];
    __shared__ u16 Hhi[16 * 264], Hlo[16 * 264];
    __shared__ float pw1s[3 * POSH];
    __shared__ float pb1s[POSH];
    __shared__ float rel_all[8][KNN][3];
    __shared__ int nbrrow[KNN];

    // weight fragments from prepped planes (registers)
    bf16x8 w1fh[8], w1fl[8], w2fh[8], w2fl[8], rBh[2], rBl[2];
    float b1v[4];
    #pragma unroll
    for (int q = 0; q < 4; ++q) {
        int e = (w * 4 + q) * 16 + lm;
        b1v[q] = ab1[h * AINNER + e];
        #pragma unroll
        for (int kc = 0; kc < 2; ++kc) {
            size_t off = ((size_t)(h * AINNER + e)) * DH + kc * 32 + lg;
            w1fh[q*2+kc] = *(const bf16x8*)&w1hi[off];
            w1fl[q*2+kc] = *(const bf16x8*)&w1lo[off];
        }
    }
    const float b2v  = ab2[h * DH + dd];
    const float pb2v = pb2[h * DH + dd];
    #pragma unroll
    for (int kc = 0; kc < 8; ++kc) {
        size_t off = ((size_t)(h * DH + dd)) * AINNER + kc * 32 + lg;
        w2fh[kc] = *(const bf16x8*)&w2hi[off];
        w2fl[kc] = *(const bf16x8*)&w2lo[off];
    }
    #pragma unroll
    for (int kc = 0; kc < 2; ++kc) {
        size_t off = ((size_t)(h * DH + dd)) * POSH + kc * 32 + lg;
        rBh[kc] = *(const bf16x8*)&rw2hi[off];
        rBl[kc] = *(const bf16x8*)&rw2lo[off];
    }

    if (t < 192) pw1s[t] = pw1[t];
    if (t < 64)  pb1s[t] = pb1[t];
    if (t < KNN) nbrrow[t] = nbr[((size_t)b * NPT + h * 128 + it) * KNN + t];
    if (t < 128) {
        int ti = t >> 4, jj = t & 15;
        int i2 = it * 8 + ti;
        int nv2 = nbr[((size_t)b * NPT + i2) * KNN + jj];
        const float* cn = canonical + ((size_t)b * NPT + nv2) * 3;
        const float* ci = canonical + ((size_t)b * NPT + i2) * 3;
        rel_all[ti][jj][0] = cn[0] - ci[0];
        rel_all[ti][jj][1] = cn[1] - ci[1];
        rel_all[ti][jj][2] = cn[2] - ci[2];
    }
    __syncthreads();

    for (int ti = 0; ti < 8; ++ti) {
        const int i = it * 8 + ti;
        // ---- Phase A: h1 = relu(rel@pw1 + pb1), trunc-split
        #pragma unroll
        for (int r = 0; r < 4; ++r) {
            int v = r * 256 + t; int j = v >> 6; int p = v & 63;
            float a = pb1s[p];
            a = fmaf(rel_all[ti][j][0], pw1s[p], a);
            a = fmaf(rel_all[ti][j][1], pw1s[64 + p], a);
            a = fmaf(rel_all[ti][j][2], pw1s[128 + p], a);
            a = fmaxf(a, 0.0f);
            u16 hi, lo; split2(a, hi, lo);
            h1hi[j * 72 + p] = hi;
            h1lo[j * 72 + p] = lo;
        }
        __syncthreads();
        // ---- Phase B: gather + rpe MFMA + X split-write + vv bf16 store
        {
            float dv[4], vw[4];
            #pragma unroll
            for (int r = 0; r < 4; ++r) {
                int j = (l >> 4) * 4 + r;
                int nv = nbrrow[2 * ti + (j >> 3)];
                size_t off = (((size_t)b * HH + (nv >> 7)) * NPT + (nv & 127) * 8 + (j & 7)) * DH + dd;
                dv[r] = Dws[off];
                vw[r] = Vws[off];
            }
            f32x4 racc = {0.f, 0.f, 0.f, 0.f};
            #pragma unroll
            for (int kc = 0; kc < 2; ++kc) {
                bf16x8 ah = *(const bf16x8*)&h1hi[lm * 72 + kc * 32 + lg];
                bf16x8 al = *(const bf16x8*)&h1lo[lm * 72 + kc * 32 + lg];
                racc = __builtin_amdgcn_mfma_f32_16x16x32_bf16(ah, rBh[kc], racc, 0, 0, 0);
                racc = __builtin_amdgcn_mfma_f32_16x16x32_bf16(al, rBh[kc], racc, 0, 0, 0);
                racc = __builtin_amdgcn_mfma_f32_16x16x32_bf16(ah, rBl[kc], racc, 0, 0, 0);
            }
            u16* vvrow = vvb + (((size_t)(b * HH + h) * NPT + i) * KNN) * DH + dd;
            #pragma unroll
            for (int r = 0; r < 4; ++r) {
                int j = (l >> 4) * 4 + r;
                float rp = racc[r] + pb2v;
                float x = dv[r] + rp;
                u16 hi, lo; split2(x, hi, lo);
                Xhi[j * 72 + dd] = hi;
                Xlo[j * 72 + dd] = lo;
                vvrow[j * DH] = f2bf_rne(vw[r] + rp);
            }
        }
        __syncthreads();
        // ---- Phase C: MLP1: H = relu(X @ W1^T + b1)
        {
            f32x4 acc1[4] = {{0,0,0,0},{0,0,0,0},{0,0,0,0},{0,0,0,0}};
            #pragma unroll
            for (int kc = 0; kc < 2; ++kc) {
                bf16x8 ah = *(const bf16x8*)&Xhi[lm * 72 + kc * 32 + lg];
                bf16x8 al = *(const bf16x8*)&Xlo[lm * 72 + kc * 32 + lg];
                #pragma unroll
                for (int q = 0; q < 4; ++q) {
                    int fi = q * 2 + kc;
                    acc1[q] = __builtin_amdgcn_mfma_f32_16x16x32_bf16(ah, w1fh[fi], acc1[q], 0, 0, 0);
                    acc1[q] = __builtin_amdgcn_mfma_f32_16x16x32_bf16(al, w1fh[fi], acc1[q], 0, 0, 0);
                    acc1[q] = __builtin_amdgcn_mfma_f32_16x16x32_bf16(ah, w1fl[fi], acc1[q], 0, 0, 0);
                }
            }
            #pragma unroll
            for (int q = 0; q < 4; ++q) {
                int ee = (w * 4 + q) * 16 + lm;
                #pragma unroll
                for (int r = 0; r < 4; ++r) {
                    int jj = (l >> 4) * 4 + r;
                    float v2 = fmaxf(acc1[q][r] + b1v[q], 0.0f);
                    u16 hi, lo; split2(v2, hi, lo);
                    Hhi[jj * 264 + ee] = hi;
                    Hlo[jj * 264 + ee] = lo;
                }
            }
        }
        __syncthreads();
        // ---- Phase D: MLP2 + in-wave softmax + attn store (no barrier needed after)
        {
            f32x4 acc2[4] = {{0,0,0,0},{0,0,0,0},{0,0,0,0},{0,0,0,0}};
            #pragma unroll
            for (int kc = 0; kc < 8; ++kc) {
                bf16x8 ah = *(const bf16x8*)&Hhi[lm * 264 + kc * 32 + lg];
                bf16x8 al = *(const bf16x8*)&Hlo[lm * 264 + kc * 32 + lg];
                int p = kc & 3;
                acc2[p] = __builtin_amdgcn_mfma_f32_16x16x32_bf16(ah, w2fh[kc], acc2[p], 0, 0, 0);
                acc2[p] = __builtin_amdgcn_mfma_f32_16x16x32_bf16(al, w2fh[kc], acc2[p], 0, 0, 0);
                acc2[p] = __builtin_amdgcn_mfma_f32_16x16x32_bf16(ah, w2fl[kc], acc2[p], 0, 0, 0);
            }
            float sim[4];
            #pragma unroll
            for (int r = 0; r < 4; ++r)
                sim[r] = ((acc2[0][r] + acc2[1][r]) + (acc2[2][r] + acc2[3][r])) + b2v;
            // softmax over j (16 rows) = 4 local rows x 4-lane group {l, l^16, l^32, l^48}
            float m = fmaxf(fmaxf(sim[0], sim[1]), fmaxf(sim[2], sim[3]));
            m = fmaxf(m, __shfl_xor(m, 16, 64));
            m = fmaxf(m, __shfl_xor(m, 32, 64));
            float ex[4], s = 0.0f;
            #pragma unroll
            for (int r = 0; r < 4; ++r) { ex[r] = __expf(sim[r] - m); s += ex[r]; }
            s += __shfl_xor(s, 16, 64);
            s += __shfl_xor(s, 32, 64);
            float inv = 1.0f / s;
            float* ao = attn + (((size_t)(b * HH + h) * NPT + i) * KNN) * DH + dd;
            #pragma unroll
            for (int r = 0; r < 4; ++r)
                ao[((l >> 4) * 4 + r) * DH] = ex[r] * inv;
        }
        // no barrier: next writes (h1 in A') are >=2 barriers past their last readers
    }
}

// ---- K4a: partial sums of attn^2 over i (128-chunk per block) -> npart
__global__ __launch_bounds__(256) void k_norm1(const float* __restrict__ attn, float* __restrict__ npart)
{
    const int j = blockIdx.x, h = blockIdx.y, bz = blockIdx.z;
    const int b = bz >> 3, ic = bz & 7;
    const int t = threadIdx.x, d = t & 63, q4 = t >> 6;
    const float* base = attn + ((size_t)(b * HH + h) * NPT) * KNN * DH + j * DH + d;
    float acc = 0.0f;
    for (int r = 0; r < 32; ++r) {
        int i = ic * 128 + q4 + r * 4;
        float a = base[(size_t)i * KNN * DH];
        acc = fmaf(a, a, acc);
    }
    __shared__ float red[256];
    red[t] = acc;
    __syncthreads();
    if (q4 == 0) {
        float s = red[d] + red[64 + d] + red[128 + d] + red[192 + d];
        npart[(((size_t)(b * HH + h) * KNN + j) * DH + d) + 16384 * ic] = s;
    }
}

// ---- K4b: reduce partials -> norm = sqrt(sum_i attn^2), (b,h,j,d)
__global__ __launch_bounds__(256) void k_norm2(const float* __restrict__ npart, float* __restrict__ nrm)
{
    int v = blockIdx.x * 256 + threadIdx.x;
    float s = 0.0f;
    #pragma unroll
    for (int ic = 0; ic < 8; ++ic) s += npart[v + 16384 * ic];
    nrm[v] = sqrtf(s);
}

// ---- K5: agg = sum_j (attn/max(nrm,1e-12)) * vv   (pure streaming)
__global__ __launch_bounds__(256) void k_agg(const float* __restrict__ attn,
                                             const float* __restrict__ nrm,
                                             const u16* __restrict__ vvb,
                                             float* __restrict__ agg)
{
    const int it = blockIdx.x, h = blockIdx.y, b = blockIdx.z, t = threadIdx.x;
    const int d = t & 63, si = t >> 6;
    const int i = it * 4 + si;
    __shared__ float rn[KNN * DH];
    for (int v = t; v < KNN * DH; v += 256)
        rn[v] = 1.0f / fmaxf(nrm[((size_t)(b * HH + h) * KNN) * DH + v], 1e-12f);
    __syncthreads();
    const float* ab = attn + (((size_t)(b * HH + h) * NPT + i) * KNN) * DH + d;
    const u16*   vb = vvb  + (((size_t)(b * HH + h) * NPT + i) * KNN) * DH + d;
    float acc = 0.0f;
    #pragma unroll
    for (int j = 0; j < KNN; ++j) {
        float a  = ab[j * DH];
        float vv = bf2f(vb[j * DH]);
        acc = fmaf(a * rn[j * DH + d], vv, acc);
    }
    agg[((size_t)b * NPT + i) * INNER + h * DH + d] = acc;
}

// ---- K6: out = agg @ w_out + b_out, f32 output
__global__ __launch_bounds__(256) void k_out(const float* __restrict__ agg,
                                             const float* __restrict__ wout,
                                             const float* __restrict__ bout,
                                             float* __restrict__ outp)
{
    __shared__ float as[8][INNER];
    const int t = threadIdx.x;
    const int g0 = blockIdx.x * 8;
    for (int v = t; v < 8 * 128; v += 256) {
        int r = v >> 7, c4 = v & 127;
        ((float4*)as[r])[c4] = ((const float4*)(agg + (size_t)(g0 + r) * INNER))[c4];
    }
    __syncthreads();
    float2 bb = ((const float2*)bout)[t];
    float a0[8], a1[8];
    #pragma unroll
    for (int r = 0; r < 8; ++r) { a0[r] = bb.x; a1[r] = bb.y; }
    for (int e = 0; e < INNER; ++e) {
        float2 w = ((const float2*)(wout + (size_t)e * EMB))[t];
        #pragma unroll
        for (int r = 0; r < 8; ++r) {
            float a = as[r][e];
            a0[r] = fmaf(a, w.x, a0[r]);
            a1[r] = fmaf(a, w.y, a1[r]);
        }
    }
    #pragma unroll
    for (int r = 0; r < 8; ++r)
        ((float2*)(outp + (size_t)(g0 + r) * EMB))[t] = make_float2(a0[r], a1[r]);
}

extern "C" void kernel_launch(void* const* d_in, const int* in_sizes, int n_in,
                              void* d_out, int out_size, void* d_ws, size_t ws_size,
                              hipStream_t stream) {
    const float* query     = (const float*)d_in[0];
    const float* key_in    = (const float*)d_in[1];
    const float* value     = (const float*)d_in[2];
    const float* canonical = (const float*)d_in[3];
    const float* wq   = (const float*)d_in[4];
    const float* wk   = (const float*)d_in[5];
    const float* wv   = (const float*)d_in[6];
    const float* wout = (const float*)d_in[7];
    const float* bout = (const float*)d_in[8];
    const float* pw1  = (const float*)d_in[9];
    const float* pb1  = (const float*)d_in[10];
    const float* pw2  = (const float*)d_in[11];
    const float* pb2  = (const float*)d_in[12];
    const float* aw1  = (const float*)d_in[13];
    const float* ab1  = (const float*)d_in[14];
    const float* aw2  = (const float*)d_in[15];
    const float* ab2  = (const float*)d_in[16];

    float* ws    = (float*)d_ws;
    float* Dws   = ws;                    // 1,048,576 f
    float* Vws   = ws + 1048576;          // 1,048,576 f
    float* aggb  = ws + 2097152;          // 1,048,576 f
    float* nrm   = ws + 3145728;          // 16,384 f
    float* npart = ws + 3162112;          // 131,072 f
    int*   nbr   = (int*)(ws + 3293184);  // 32,768 i32
    float* attn  = ws + 3325952;          // 16,777,216 f (end 20,103,168 f = 80.4 MB)
    u16*   u16b  = (u16*)(ws + 20103168); // 16B-aligned
    u16*   w1hi  = u16b;                  // 131,072 u16
    u16*   w1lo  = u16b + 131072;
    u16*   w2hi  = u16b + 262144;
    u16*   w2lo  = u16b + 393216;
    u16*   rw2hi = u16b + 524288;         // 32,768 u16
    u16*   rw2lo = u16b + 557056;
    u16*   vvb   = u16b + 589824;         // 16,777,216 u16 (total ~115.1 MB)

    k_prep<<<1152, 256, 0, stream>>>(aw1, aw2, pw2, w1hi, w1lo, w2hi, w2lo, rw2hi, rw2lo);
    k_proj<<<256, 256, 0, stream>>>(query, key_in, value, wq, wk, wv, Dws, Vws);
    k_knn<<<dim3(NPT, BS), 256, 0, stream>>>(canonical, nbr);
    k_attn<<<dim3(128, HH, BS), 256, 0, stream>>>(Dws, Vws, canonical, nbr, pw1, pb1, pb2,
                                                  ab1, ab2, w1hi, w1lo, w2hi, w2lo,
                                                  rw2hi, rw2lo, vvb, attn);
    k_norm1<<<dim3(KNN, HH, BS * 8), 256, 0, stream>>>(attn, npart);
    k_norm2<<<64, 256, 0, stream>>>(npart, nrm);
    k_agg<<<dim3(256, HH, BS), 256, 0, stream>>>(attn, nrm, vvb, aggb);
    k_out<<<256, 256, 0, stream>>>(aggb, wout, bout, (float*)d_out);
}

// Round 6
// 229.503 us; speedup vs baseline: 4.0586x; 1.4098x over previous
//
#include <hip/hip_runtime.h>

// MultiHeadVectorAttention — round 6: fix A-frag wave-row offset in k_projM/k_outM.
// bs=2, n=1024, H=8, DH=64, K=16, EMB=INNER=512, AINNER=256, POSH=64.

#define BS 2
#define NPT 1024
#define HH 8
#define DH 64
#define KNN 16
#define EMB 512
#define INNER 512
#define AINNER 256
#define POSH 64

typedef unsigned short u16;
typedef unsigned int u32;
typedef __attribute__((ext_vector_type(8))) short bf16x8;
typedef __attribute__((ext_vector_type(4))) float f32x4;

__device__ __forceinline__ float bf2f(u16 b) { union { u32 u; float f; } v; v.u = ((u32)b) << 16; return v.f; }
__device__ __forceinline__ u16 f2bf_rne(float f) {
    u32 x = __float_as_uint(f);
    u32 r = x + 0x7fffu + ((x >> 16) & 1u);
    return (u16)(r >> 16);
}
// truncation split: hi = trunc-bf16(f), lo = trunc-bf16(f - hi).
__device__ __forceinline__ void split2(float f, u16& hi, u16& lo) {
    u32 bits = __float_as_uint(f);
    hi = (u16)(bits >> 16);
    float resid = f - __uint_as_float(bits & 0xffff0000u);
    lo = (u16)(__float_as_uint(resid) >> 16);
}

// ---- K0a: split q/k/v into bf16 hi/lo planes (key negated: D = q@wq + (-k)@wk).
__global__ __launch_bounds__(256) void k_split_lin(const float* __restrict__ query,
                                                   const float* __restrict__ key_in,
                                                   const float* __restrict__ value,
                                                   u16* __restrict__ qhi, u16* __restrict__ qlo,
                                                   u16* __restrict__ khi, u16* __restrict__ klo,
                                                   u16* __restrict__ vhi, u16* __restrict__ vlo)
{
    const int m = blockIdx.y;
    const int v = (blockIdx.x * 256 + threadIdx.x) * 4;
    const float* src; u16* dh; u16* dl;
    switch (m) {
        case 0:  src = query;  dh = qhi; dl = qlo; break;
        case 1:  src = key_in; dh = khi; dl = klo; break;
        default: src = value;  dh = vhi; dl = vlo; break;
    }
    float4 f = *(const float4*)&src[v];
    if (m == 1) { f.x = -f.x; f.y = -f.y; f.z = -f.z; f.w = -f.w; }
    ushort4 h4, l4;
    split2(f.x, h4.x, l4.x); split2(f.y, h4.y, l4.y);
    split2(f.z, h4.z, l4.z); split2(f.w, h4.w, l4.w);
    *(ushort4*)&dh[v] = h4;
    *(ushort4*)&dl[v] = l4;
}

// ---- K0b: transpose+split 512x512 weights: plane[c*512+e] = w[e*512+c].
__global__ __launch_bounds__(256) void k_split_T(const float* __restrict__ wq,
                                                 const float* __restrict__ wk,
                                                 const float* __restrict__ wv,
                                                 const float* __restrict__ wout,
                                                 u16* __restrict__ o0h, u16* __restrict__ o0l,
                                                 u16* __restrict__ o1h, u16* __restrict__ o1l,
                                                 u16* __restrict__ o2h, u16* __restrict__ o2l,
                                                 u16* __restrict__ o3h, u16* __restrict__ o3l)
{
    __shared__ float S[64][65];
    const int t = threadIdx.x;
    const int e0 = blockIdx.x * 64, c0 = blockIdx.y * 64;
    const float* src; u16* dh; u16* dl;
    switch (blockIdx.z) {
        case 0:  src = wq;   dh = o0h; dl = o0l; break;
        case 1:  src = wk;   dh = o1h; dl = o1l; break;
        case 2:  src = wv;   dh = o2h; dl = o2l; break;
        default: src = wout; dh = o3h; dl = o3l; break;
    }
    #pragma unroll
    for (int s = 0; s < 16; ++s) {
        int v = s * 256 + t; int r = v >> 6, c = v & 63;
        S[r][c] = src[(size_t)(e0 + r) * 512 + c0 + c];
    }
    __syncthreads();
    #pragma unroll
    for (int s = 0; s < 16; ++s) {
        int v = s * 256 + t; int c = v >> 6, e = v & 63;
        u16 hi, lo; split2(S[e][c], hi, lo);
        size_t off = (size_t)(c0 + c) * 512 + e0 + e;
        dh[off] = hi; dl[off] = lo;
    }
}

// ---- K0c: pre-split aw1/aw2/rw2 planes.
__global__ __launch_bounds__(256) void k_prep(const float* __restrict__ aw1,
                                              const float* __restrict__ aw2,
                                              const float* __restrict__ pw2,
                                              u16* __restrict__ w1hi, u16* __restrict__ w1lo,
                                              u16* __restrict__ w2hi, u16* __restrict__ w2lo,
                                              u16* __restrict__ rw2hi, u16* __restrict__ rw2lo)
{
    int v = blockIdx.x * 256 + threadIdx.x;
    float f; u16* dhi; u16* dlo; int idx;
    if (v < 131072) { f = aw1[v]; dhi = w1hi; dlo = w1lo; idx = v; }
    else if (v < 262144) { idx = v - 131072; f = aw2[idx]; dhi = w2hi; dlo = w2lo; }
    else {
        idx = v - 262144;
        int p = idx & 63; int hd = idx >> 6;
        int h = hd >> 6;  int d = hd & 63;
        f = pw2[(size_t)p * INNER + h * DH + d];
        dhi = rw2hi; dlo = rw2lo;
    }
    u16 hi, lo; split2(f, hi, lo);
    dhi[idx] = hi; dlo[idx] = lo;
}

// ---- K1: MFMA projection GEMM. D = q@wq + (-k)@wk, V = v@wv.
// Block: 64 rows x 64 cols; grid (32, 8); wave w = rows w*16..+15; BK=32.
__global__ __launch_bounds__(256) void k_projM(const u16* __restrict__ qhi, const u16* __restrict__ qlo,
                                               const u16* __restrict__ khi, const u16* __restrict__ klo,
                                               const u16* __restrict__ vhi, const u16* __restrict__ vlo,
                                               const u16* __restrict__ wqh, const u16* __restrict__ wql,
                                               const u16* __restrict__ wkh, const u16* __restrict__ wkl,
                                               const u16* __restrict__ wvh, const u16* __restrict__ wvl,
                                               float* __restrict__ Dws, float* __restrict__ Vws)
{
    __shared__ u16 S[12][64 * 40];
    const int t = threadIdx.x, l = t & 63, w = t >> 6;
    const int lm = l & 15, lg = (l >> 4) * 8;
    const int g0 = blockIdx.x * 64, c0 = blockIdx.y * 64;
    const int sr = t >> 2, sc = (t & 3) * 8;

    f32x4 accD[4] = {{0,0,0,0},{0,0,0,0},{0,0,0,0},{0,0,0,0}};
    f32x4 accV[4] = {{0,0,0,0},{0,0,0,0},{0,0,0,0},{0,0,0,0}};

    for (int ks = 0; ks < 16; ++ks) {
        const int k0 = ks * 32;
        if (ks) __syncthreads();
        #define STG(p, base, rb) \
            *(uint4*)&S[p][sr * 40 + sc] = *(const uint4*)&(base)[(size_t)((rb) + sr) * 512 + k0 + sc];
        STG(0, qhi, g0) STG(1, qlo, g0) STG(2, khi, g0) STG(3, klo, g0)
        STG(4, vhi, g0) STG(5, vlo, g0)
        STG(6, wqh, c0) STG(7, wql, c0) STG(8, wkh, c0) STG(9, wkl, c0)
        STG(10, wvh, c0) STG(11, wvl, c0)
        #undef STG
        __syncthreads();

        const int ao = (w * 16 + lm) * 40 + lg;   // FIX: wave-row offset in A-frag
        bf16x8 aqh = *(const bf16x8*)&S[0][ao];
        bf16x8 aql = *(const bf16x8*)&S[1][ao];
        bf16x8 akh = *(const bf16x8*)&S[2][ao];
        bf16x8 akl = *(const bf16x8*)&S[3][ao];
        bf16x8 avh = *(const bf16x8*)&S[4][ao];
        bf16x8 avl = *(const bf16x8*)&S[5][ao];
        #pragma unroll
        for (int ct = 0; ct < 4; ++ct) {
            const int bo = (ct * 16 + lm) * 40 + lg;
            bf16x8 bqh = *(const bf16x8*)&S[6][bo];
            bf16x8 bql = *(const bf16x8*)&S[7][bo];
            bf16x8 bkh = *(const bf16x8*)&S[8][bo];
            bf16x8 bkl = *(const bf16x8*)&S[9][bo];
            bf16x8 bvh = *(const bf16x8*)&S[10][bo];
            bf16x8 bvl = *(const bf16x8*)&S[11][bo];
            accD[ct] = __builtin_amdgcn_mfma_f32_16x16x32_bf16(aqh, bqh, accD[ct], 0, 0, 0);
            accD[ct] = __builtin_amdgcn_mfma_f32_16x16x32_bf16(aql, bqh, accD[ct], 0, 0, 0);
            accD[ct] = __builtin_amdgcn_mfma_f32_16x16x32_bf16(aqh, bql, accD[ct], 0, 0, 0);
            accD[ct] = __builtin_amdgcn_mfma_f32_16x16x32_bf16(akh, bkh, accD[ct], 0, 0, 0);
            accD[ct] = __builtin_amdgcn_mfma_f32_16x16x32_bf16(akl, bkh, accD[ct], 0, 0, 0);
            accD[ct] = __builtin_amdgcn_mfma_f32_16x16x32_bf16(akh, bkl, accD[ct], 0, 0, 0);
            accV[ct] = __builtin_amdgcn_mfma_f32_16x16x32_bf16(avh, bvh, accV[ct], 0, 0, 0);
            accV[ct] = __builtin_amdgcn_mfma_f32_16x16x32_bf16(avl, bvh, accV[ct], 0, 0, 0);
            accV[ct] = __builtin_amdgcn_mfma_f32_16x16x32_bf16(avh, bvl, accV[ct], 0, 0, 0);
        }
    }

    const int b = blockIdx.x >> 4;
    const int h = blockIdx.y;
    #pragma unroll
    for (int ct = 0; ct < 4; ++ct) {
        #pragma unroll
        for (int r = 0; r < 4; ++r) {
            int g = g0 + w * 16 + (l >> 4) * 4 + r;
            int i = g & 1023;
            size_t off = (((size_t)(b * HH + h)) * NPT + i) * DH + ct * 16 + lm;
            Dws[off] = accD[ct][r];
            Vws[off] = accV[ct][r];
        }
    }
}

// ---- K2: KNN
__global__ __launch_bounds__(256) void k_knn(const float* __restrict__ canonical, int* __restrict__ nbr)
{
    const int i = blockIdx.x, b = blockIdx.y, t = threadIdx.x;
    const int l = t & 63, w = t >> 6;
    __shared__ float d2[NPT];
    __shared__ float wv4[4];
    __shared__ int   wi4[4];
    const float* cb = canonical + (size_t)b * NPT * 3;
    const float xi = cb[i*3+0], yi = cb[i*3+1], zi = cb[i*3+2];
    for (int j = t; j < NPT; j += 256) {
        float dx = __fsub_rn(cb[j*3+0], xi);
        float dy = __fsub_rn(cb[j*3+1], yi);
        float dz = __fsub_rn(cb[j*3+2], zi);
        d2[j] = __fadd_rn(__fadd_rn(__fmul_rn(dx,dx), __fmul_rn(dy,dy)), __fmul_rn(dz,dz));
    }
    __syncthreads();
    for (int sel = 0; sel < KNN; ++sel) {
        float bv = __builtin_inff(); int bi = NPT;
        for (int j = t; j < NPT; j += 256) {
            float v = d2[j];
            if (v < bv) { bv = v; bi = j; }
        }
        #pragma unroll
        for (int m = 32; m >= 1; m >>= 1) {
            float ov = __shfl_xor(bv, m, 64);
            int   oi = __shfl_xor(bi, m, 64);
            if (ov < bv || (ov == bv && oi < bi)) { bv = ov; bi = oi; }
        }
        if (l == 0) { wv4[w] = bv; wi4[w] = bi; }
        __syncthreads();
        if (t == 0) {
            float fv = wv4[0]; int fi = wi4[0];
            #pragma unroll
            for (int q = 1; q < 4; ++q) {
                float ov = wv4[q]; int oi = wi4[q];
                if (ov < fv || (ov == fv && oi < fi)) { fv = ov; fi = oi; }
            }
            nbr[((size_t)b*NPT + i)*KNN + sel] = fi;
            d2[fi] = __builtin_inff();
        }
        __syncthreads();
    }
}

// ---- K3: MFMA attn kernel (unchanged, verified)
__global__ __launch_bounds__(256) void k_attn(const float* __restrict__ Dws,
                                              const float* __restrict__ Vws,
                                              const float* __restrict__ canonical,
                                              const int* __restrict__ nbr,
                                              const float* __restrict__ pw1,
                                              const float* __restrict__ pb1,
                                              const float* __restrict__ pb2,
                                              const float* __restrict__ ab1,
                                              const float* __restrict__ ab2,
                                              const u16* __restrict__ w1hi, const u16* __restrict__ w1lo,
                                              const u16* __restrict__ w2hi, const u16* __restrict__ w2lo,
                                              const u16* __restrict__ rw2hi, const u16* __restrict__ rw2lo,
                                              u16* __restrict__ vvb,
                                              float* __restrict__ attn)
{
    const int it = blockIdx.x, h = blockIdx.y, b = blockIdx.z, t = threadIdx.x;
    const int l = t & 63, w = t >> 6;
    const int lm = l & 15, lg = (l >> 4) * 8;
    const int dd = w * 16 + lm;

    __shared__ u16 h1hi[16 * 72], h1lo[16 * 72];
    __shared__ u16 Xhi[16 * 72],  Xlo[16 * 72];
    __shared__ u16 Hhi[16 * 264], Hlo[16 * 264];
    __shared__ float pw1s[3 * POSH];
    __shared__ float pb1s[POSH];
    __shared__ float rel_all[8][KNN][3];
    __shared__ int nbrrow[KNN];

    bf16x8 w1fh[8], w1fl[8], w2fh[8], w2fl[8], rBh[2], rBl[2];
    float b1v[4];
    #pragma unroll
    for (int q = 0; q < 4; ++q) {
        int e = (w * 4 + q) * 16 + lm;
        b1v[q] = ab1[h * AINNER + e];
        #pragma unroll
        for (int kc = 0; kc < 2; ++kc) {
            size_t off = ((size_t)(h * AINNER + e)) * DH + kc * 32 + lg;
            w1fh[q*2+kc] = *(const bf16x8*)&w1hi[off];
            w1fl[q*2+kc] = *(const bf16x8*)&w1lo[off];
        }
    }
    const float b2v  = ab2[h * DH + dd];
    const float pb2v = pb2[h * DH + dd];
    #pragma unroll
    for (int kc = 0; kc < 8; ++kc) {
        size_t off = ((size_t)(h * DH + dd)) * AINNER + kc * 32 + lg;
        w2fh[kc] = *(const bf16x8*)&w2hi[off];
        w2fl[kc] = *(const bf16x8*)&w2lo[off];
    }
    #pragma unroll
    for (int kc = 0; kc < 2; ++kc) {
        size_t off = ((size_t)(h * DH + dd)) * POSH + kc * 32 + lg;
        rBh[kc] = *(const bf16x8*)&rw2hi[off];
        rBl[kc] = *(const bf16x8*)&rw2lo[off];
    }

    if (t < 192) pw1s[t] = pw1[t];
    if (t < 64)  pb1s[t] = pb1[t];
    if (t < KNN) nbrrow[t] = nbr[((size_t)b * NPT + h * 128 + it) * KNN + t];
    if (t < 128) {
        int ti = t >> 4, jj = t & 15;
        int i2 = it * 8 + ti;
        int nv2 = nbr[((size_t)b * NPT + i2) * KNN + jj];
        const float* cn = canonical + ((size_t)b * NPT + nv2) * 3;
        const float* ci = canonical + ((size_t)b * NPT + i2) * 3;
        rel_all[ti][jj][0] = cn[0] - ci[0];
        rel_all[ti][jj][1] = cn[1] - ci[1];
        rel_all[ti][jj][2] = cn[2] - ci[2];
    }
    __syncthreads();

    for (int ti = 0; ti < 8; ++ti) {
        const int i = it * 8 + ti;
        #pragma unroll
        for (int r = 0; r < 4; ++r) {
            int v = r * 256 + t; int j = v >> 6; int p = v & 63;
            float a = pb1s[p];
            a = fmaf(rel_all[ti][j][0], pw1s[p], a);
            a = fmaf(rel_all[ti][j][1], pw1s[64 + p], a);
            a = fmaf(rel_all[ti][j][2], pw1s[128 + p], a);
            a = fmaxf(a, 0.0f);
            u16 hi, lo; split2(a, hi, lo);
            h1hi[j * 72 + p] = hi;
            h1lo[j * 72 + p] = lo;
        }
        __syncthreads();
        {
            float dv[4], vw[4];
            #pragma unroll
            for (int r = 0; r < 4; ++r) {
                int j = (l >> 4) * 4 + r;
                int nv = nbrrow[2 * ti + (j >> 3)];
                size_t off = (((size_t)b * HH + (nv >> 7)) * NPT + (nv & 127) * 8 + (j & 7)) * DH + dd;
                dv[r] = Dws[off];
                vw[r] = Vws[off];
            }
            f32x4 racc = {0.f, 0.f, 0.f, 0.f};
            #pragma unroll
            for (int kc = 0; kc < 2; ++kc) {
                bf16x8 ah = *(const bf16x8*)&h1hi[lm * 72 + kc * 32 + lg];
                bf16x8 al = *(const bf16x8*)&h1lo[lm * 72 + kc * 32 + lg];
                racc = __builtin_amdgcn_mfma_f32_16x16x32_bf16(ah, rBh[kc], racc, 0, 0, 0);
                racc = __builtin_amdgcn_mfma_f32_16x16x32_bf16(al, rBh[kc], racc, 0, 0, 0);
                racc = __builtin_amdgcn_mfma_f32_16x16x32_bf16(ah, rBl[kc], racc, 0, 0, 0);
            }
            u16* vvrow = vvb + (((size_t)(b * HH + h) * NPT + i) * KNN) * DH + dd;
            #pragma unroll
            for (int r = 0; r < 4; ++r) {
                int j = (l >> 4) * 4 + r;
                float rp = racc[r] + pb2v;
                float x = dv[r] + rp;
                u16 hi, lo; split2(x, hi, lo);
                Xhi[j * 72 + dd] = hi;
                Xlo[j * 72 + dd] = lo;
                vvrow[j * DH] = f2bf_rne(vw[r] + rp);
            }
        }
        __syncthreads();
        {
            f32x4 acc1[4] = {{0,0,0,0},{0,0,0,0},{0,0,0,0},{0,0,0,0}};
            #pragma unroll
            for (int kc = 0; kc < 2; ++kc) {
                bf16x8 ah = *(const bf16x8*)&Xhi[lm * 72 + kc * 32 + lg];
                bf16x8 al = *(const bf16x8*)&Xlo[lm * 72 + kc * 32 + lg];
                #pragma unroll
                for (int q = 0; q < 4; ++q) {
                    int fi = q * 2 + kc;
                    acc1[q] = __builtin_amdgcn_mfma_f32_16x16x32_bf16(ah, w1fh[fi], acc1[q], 0, 0, 0);
                    acc1[q] = __builtin_amdgcn_mfma_f32_16x16x32_bf16(al, w1fh[fi], acc1[q], 0, 0, 0);
                    acc1[q] = __builtin_amdgcn_mfma_f32_16x16x32_bf16(ah, w1fl[fi], acc1[q], 0, 0, 0);
                }
            }
            #pragma unroll
            for (int q = 0; q < 4; ++q) {
                int ee = (w * 4 + q) * 16 + lm;
                #pragma unroll
                for (int r = 0; r < 4; ++r) {
                    int jj = (l >> 4) * 4 + r;
                    float v2 = fmaxf(acc1[q][r] + b1v[q], 0.0f);
                    u16 hi, lo; split2(v2, hi, lo);
                    Hhi[jj * 264 + ee] = hi;
                    Hlo[jj * 264 + ee] = lo;
                }
            }
        }
        __syncthreads();
        {
            f32x4 acc2[4] = {{0,0,0,0},{0,0,0,0},{0,0,0,0},{0,0,0,0}};
            #pragma unroll
            for (int kc = 0; kc < 8; ++kc) {
                bf16x8 ah = *(const bf16x8*)&Hhi[lm * 264 + kc * 32 + lg];
                bf16x8 al = *(const bf16x8*)&Hlo[lm * 264 + kc * 32 + lg];
                int p = kc & 3;
                acc2[p] = __builtin_amdgcn_mfma_f32_16x16x32_bf16(ah, w2fh[kc], acc2[p], 0, 0, 0);
                acc2[p] = __builtin_amdgcn_mfma_f32_16x16x32_bf16(al, w2fh[kc], acc2[p], 0, 0, 0);
                acc2[p] = __builtin_amdgcn_mfma_f32_16x16x32_bf16(ah, w2fl[kc], acc2[p], 0, 0, 0);
            }
            float sim[4];
            #pragma unroll
            for (int r = 0; r < 4; ++r)
                sim[r] = ((acc2[0][r] + acc2[1][r]) + (acc2[2][r] + acc2[3][r])) + b2v;
            float m = fmaxf(fmaxf(sim[0], sim[1]), fmaxf(sim[2], sim[3]));
            m = fmaxf(m, __shfl_xor(m, 16, 64));
            m = fmaxf(m, __shfl_xor(m, 32, 64));
            float ex[4], s = 0.0f;
            #pragma unroll
            for (int r = 0; r < 4; ++r) { ex[r] = __expf(sim[r] - m); s += ex[r]; }
            s += __shfl_xor(s, 16, 64);
            s += __shfl_xor(s, 32, 64);
            float inv = 1.0f / s;
            float* ao = attn + (((size_t)(b * HH + h) * NPT + i) * KNN) * DH + dd;
            #pragma unroll
            for (int r = 0; r < 4; ++r)
                ao[((l >> 4) * 4 + r) * DH] = ex[r] * inv;
        }
    }
}

// ---- K4a/K4b: norm reduction
__global__ __launch_bounds__(256) void k_norm1(const float* __restrict__ attn, float* __restrict__ npart)
{
    const int j = blockIdx.x, h = blockIdx.y, bz = blockIdx.z;
    const int b = bz >> 3, ic = bz & 7;
    const int t = threadIdx.x, d = t & 63, q4 = t >> 6;
    const float* base = attn + ((size_t)(b * HH + h) * NPT) * KNN * DH + j * DH + d;
    float acc = 0.0f;
    for (int r = 0; r < 32; ++r) {
        int i = ic * 128 + q4 + r * 4;
        float a = base[(size_t)i * KNN * DH];
        acc = fmaf(a, a, acc);
    }
    __shared__ float red[256];
    red[t] = acc;
    __syncthreads();
    if (q4 == 0) {
        float s = red[d] + red[64 + d] + red[128 + d] + red[192 + d];
        npart[(((size_t)(b * HH + h) * KNN + j) * DH + d) + 16384 * ic] = s;
    }
}

__global__ __launch_bounds__(256) void k_norm2(const float* __restrict__ npart, float* __restrict__ nrm)
{
    int v = blockIdx.x * 256 + threadIdx.x;
    float s = 0.0f;
    #pragma unroll
    for (int ic = 0; ic < 8; ++ic) s += npart[v + 16384 * ic];
    nrm[v] = sqrtf(s);
}

// ---- K5: agg = sum_j (attn/max(nrm,1e-12)) * vv, output split to bf16 hi/lo planes
__global__ __launch_bounds__(256) void k_agg(const float* __restrict__ attn,
                                             const float* __restrict__ nrm,
                                             const u16* __restrict__ vvb,
                                             u16* __restrict__ agghi,
                                             u16* __restrict__ agglo)
{
    const int it = blockIdx.x, h = blockIdx.y, b = blockIdx.z, t = threadIdx.x;
    const int d = t & 63, si = t >> 6;
    const int i = it * 4 + si;
    __shared__ float rn[KNN * DH];
    for (int v = t; v < KNN * DH; v += 256)
        rn[v] = 1.0f / fmaxf(nrm[((size_t)(b * HH + h) * KNN) * DH + v], 1e-12f);
    __syncthreads();
    const float* ab = attn + (((size_t)(b * HH + h) * NPT + i) * KNN) * DH + d;
    const u16*   vb = vvb  + (((size_t)(b * HH + h) * NPT + i) * KNN) * DH + d;
    float acc = 0.0f;
    #pragma unroll
    for (int j = 0; j < KNN; ++j) {
        float a  = ab[j * DH];
        float vv = bf2f(vb[j * DH]);
        acc = fmaf(a * rn[j * DH + d], vv, acc);
    }
    size_t off = ((size_t)b * NPT + i) * INNER + h * DH + d;
    u16 hi, lo; split2(acc, hi, lo);
    agghi[off] = hi;
    agglo[off] = lo;
}

// ---- K6: MFMA out GEMM: out = agg @ w_out + b_out.
__global__ __launch_bounds__(256) void k_outM(const u16* __restrict__ agghi, const u16* __restrict__ agglo,
                                              const u16* __restrict__ wth, const u16* __restrict__ wtl,
                                              const float* __restrict__ bout,
                                              float* __restrict__ outp)
{
    __shared__ u16 S[4][64 * 40];
    const int t = threadIdx.x, l = t & 63, w = t >> 6;
    const int lm = l & 15, lg = (l >> 4) * 8;
    const int g0 = blockIdx.x * 64, c0 = blockIdx.y * 64;
    const int sr = t >> 2, sc = (t & 3) * 8;

    f32x4 acc[4] = {{0,0,0,0},{0,0,0,0},{0,0,0,0},{0,0,0,0}};
    float bv4[4];
    #pragma unroll
    for (int ct = 0; ct < 4; ++ct) bv4[ct] = bout[c0 + ct * 16 + lm];

    for (int ks = 0; ks < 16; ++ks) {
        const int k0 = ks * 32;
        if (ks) __syncthreads();
        *(uint4*)&S[0][sr * 40 + sc] = *(const uint4*)&agghi[(size_t)(g0 + sr) * 512 + k0 + sc];
        *(uint4*)&S[1][sr * 40 + sc] = *(const uint4*)&agglo[(size_t)(g0 + sr) * 512 + k0 + sc];
        *(uint4*)&S[2][sr * 40 + sc] = *(const uint4*)&wth[(size_t)(c0 + sr) * 512 + k0 + sc];
        *(uint4*)&S[3][sr * 40 + sc] = *(const uint4*)&wtl[(size_t)(c0 + sr) * 512 + k0 + sc];
        __syncthreads();

        const int ao = (w * 16 + lm) * 40 + lg;   // FIX: wave-row offset in A-frag
        bf16x8 ah = *(const bf16x8*)&S[0][ao];
        bf16x8 al = *(const bf16x8*)&S[1][ao];
        #pragma unroll
        for (int ct = 0; ct < 4; ++ct) {
            const int bo = (ct * 16 + lm) * 40 + lg;
            bf16x8 bh = *(const bf16x8*)&S[2][bo];
            bf16x8 bl = *(const bf16x8*)&S[3][bo];
            acc[ct] = __builtin_amdgcn_mfma_f32_16x16x32_bf16(ah, bh, acc[ct], 0, 0, 0);
            acc[ct] = __builtin_amdgcn_mfma_f32_16x16x32_bf16(al, bh, acc[ct], 0, 0, 0);
            acc[ct] = __builtin_amdgcn_mfma_f32_16x16x32_bf16(ah, bl, acc[ct], 0, 0, 0);
        }
    }
    #pragma unroll
    for (int ct = 0; ct < 4; ++ct) {
        #pragma unroll
        for (int r = 0; r < 4; ++r) {
            int g = g0 + w * 16 + (l >> 4) * 4 + r;
            outp[(size_t)g * 512 + c0 + ct * 16 + lm] = acc[ct][r] + bv4[ct];
        }
    }
}

extern "C" void kernel_launch(void* const* d_in, const int* in_sizes, int n_in,
                              void* d_out, int out_size, void* d_ws, size_t ws_size,
                              hipStream_t stream) {
    const float* query     = (const float*)d_in[0];
    const float* key_in    = (const float*)d_in[1];
    const float* value     = (const float*)d_in[2];
    const float* canonical = (const float*)d_in[3];
    const float* wq   = (const float*)d_in[4];
    const float* wk   = (const float*)d_in[5];
    const float* wv   = (const float*)d_in[6];
    const float* wout = (const float*)d_in[7];
    const float* bout = (const float*)d_in[8];
    const float* pw1  = (const float*)d_in[9];
    const float* pb1  = (const float*)d_in[10];
    const float* pw2  = (const float*)d_in[11];
    const float* pb2  = (const float*)d_in[12];
    const float* aw1  = (const float*)d_in[13];
    const float* ab1  = (const float*)d_in[14];
    const float* aw2  = (const float*)d_in[15];
    const float* ab2  = (const float*)d_in[16];

    float* ws    = (float*)d_ws;
    float* Dws   = ws;                    // 1,048,576 f
    float* Vws   = ws + 1048576;          // 1,048,576 f
    float* aggp  = ws + 2097152;          // 1,048,576 f, reused as agg hi/lo u16 planes
    float* nrm   = ws + 3145728;          // 16,384 f
    float* npart = ws + 3162112;          // 131,072 f
    int*   nbr   = (int*)(ws + 3293184);  // 32,768 i32
    float* attn  = ws + 3325952;          // 16,777,216 f

    u16* agghi = (u16*)aggp;              // 1,048,576 u16
    u16* agglo = agghi + 1048576;

    // input/weight planes alias the attn region (consumed by projM before attn is written)
    u16* pl   = (u16*)attn;
    u16* qhi  = pl;                u16* qlo  = pl + 1048576;
    u16* khi  = pl + 2097152;      u16* klo  = pl + 3145728;
    u16* vhi  = pl + 4194304;      u16* vlo  = pl + 5242880;
    u16* wqTh = pl + 6291456;      u16* wqTl = pl + 6553600;
    u16* wkTh = pl + 6815744;      u16* wkTl = pl + 7077888;
    u16* wvTh = pl + 7340032;      u16* wvTl = pl + 7602176;

    u16* u16b  = (u16*)(ws + 20103168);
    u16* w1hi  = u16b;
    u16* w1lo  = u16b + 131072;
    u16* w2hi  = u16b + 262144;
    u16* w2lo  = u16b + 393216;
    u16* rw2hi = u16b + 524288;
    u16* rw2lo = u16b + 557056;
    u16* vvb   = u16b + 589824;           // 16,777,216 u16
    u16* wouTh = u16b + 17367040;
    u16* wouTl = u16b + 17629184;         // end ~116 MB total ws

    k_split_lin<<<dim3(1024, 3), 256, 0, stream>>>(query, key_in, value,
                                                   qhi, qlo, khi, klo, vhi, vlo);
    k_split_T<<<dim3(8, 8, 4), 256, 0, stream>>>(wq, wk, wv, wout,
                                                 wqTh, wqTl, wkTh, wkTl, wvTh, wvTl, wouTh, wouTl);
    k_prep<<<1152, 256, 0, stream>>>(aw1, aw2, pw2, w1hi, w1lo, w2hi, w2lo, rw2hi, rw2lo);
    k_projM<<<dim3(32, 8), 256, 0, stream>>>(qhi, qlo, khi, klo, vhi, vlo,
                                             wqTh, wqTl, wkTh, wkTl, wvTh, wvTl, Dws, Vws);
    k_knn<<<dim3(NPT, BS), 256, 0, stream>>>(canonical, nbr);
    k_attn<<<dim3(128, HH, BS), 256, 0, stream>>>(Dws, Vws, canonical, nbr, pw1, pb1, pb2,
                                                  ab1, ab2, w1hi, w1lo, w2hi, w2lo,
                                                  rw2hi, rw2lo, vvb, attn);
    k_norm1<<<dim3(KNN, HH, BS * 8), 256, 0, stream>>>(attn, npart);
    k_norm2<<<64, 256, 0, stream>>>(npart, nrm);
    k_agg<<<dim3(256, HH, BS), 256, 0, stream>>>(attn, nrm, vvb, agghi, agglo);
    k_outM<<<dim3(32, 8), 256, 0, stream>>>(agghi, agglo, wouTh, wouTl, bout, (float*)d_out);
}

// Round 7
// 195.230 us; speedup vs baseline: 4.7711x; 1.1755x over previous
//
#include <hip/hip_runtime.h>

// MultiHeadVectorAttention — round 7: k_attn 2-pass (rne weights, fewer regs),
// gather prefetch; wave-per-i barrierless KNN; fused norm2->agg; fused pre-split.
// bs=2, n=1024, H=8, DH=64, K=16, EMB=INNER=512, AINNER=256, POSH=64.

#define BS 2
#define NPT 1024
#define HH 8
#define DH 64
#define KNN 16
#define EMB 512
#define INNER 512
#define AINNER 256
#define POSH 64

typedef unsigned short u16;
typedef unsigned int u32;
typedef __attribute__((ext_vector_type(8))) short bf16x8;
typedef __attribute__((ext_vector_type(4))) float f32x4;

__device__ __forceinline__ float bf2f(u16 b) { union { u32 u; float f; } v; v.u = ((u32)b) << 16; return v.f; }
__device__ __forceinline__ u16 f2bf_rne(float f) {
    u32 x = __float_as_uint(f);
    u32 r = x + 0x7fffu + ((x >> 16) & 1u);
    return (u16)(r >> 16);
}
// truncation split: hi = trunc-bf16(f), lo = rne-bf16(f - hi). total rel err ~2^-17.
__device__ __forceinline__ void split2(float f, u16& hi, u16& lo) {
    u32 bits = __float_as_uint(f);
    hi = (u16)(bits >> 16);
    float resid = f - __uint_as_float(bits & 0xffff0000u);
    lo = (u16)(__float_as_uint(resid) >> 16);
}

// ---- K0a: fused: split q/k(neg)/v into hi/lo planes  +  rne-quantize attn weights.
// blocks [0,3072): lin split; blocks [3072,4224): w1/w2/rw2 rne planes.
__global__ __launch_bounds__(256) void k_pre(const float* __restrict__ query,
                                             const float* __restrict__ key_in,
                                             const float* __restrict__ value,
                                             const float* __restrict__ aw1,
                                             const float* __restrict__ aw2,
                                             const float* __restrict__ pw2,
                                             u16* __restrict__ qhi, u16* __restrict__ qlo,
                                             u16* __restrict__ khi, u16* __restrict__ klo,
                                             u16* __restrict__ vhi, u16* __restrict__ vlo,
                                             u16* __restrict__ w1hi, u16* __restrict__ w2hi,
                                             u16* __restrict__ rw2hi)
{
    const int bx = blockIdx.x, t = threadIdx.x;
    if (bx < 3072) {
        const int m = bx >> 10;
        const int v = (((bx & 1023) * 256) + t) * 4;
        const float* src; u16* dh; u16* dl;
        switch (m) {
            case 0:  src = query;  dh = qhi; dl = qlo; break;
            case 1:  src = key_in; dh = khi; dl = klo; break;
            default: src = value;  dh = vhi; dl = vlo; break;
        }
        float4 f = *(const float4*)&src[v];
        if (m == 1) { f.x = -f.x; f.y = -f.y; f.z = -f.z; f.w = -f.w; }
        ushort4 h4, l4;
        split2(f.x, h4.x, l4.x); split2(f.y, h4.y, l4.y);
        split2(f.z, h4.z, l4.z); split2(f.w, h4.w, l4.w);
        *(ushort4*)&dh[v] = h4;
        *(ushort4*)&dl[v] = l4;
    } else {
        int idx = (bx - 3072) * 256 + t;
        if (idx < 131072) {
            w1hi[idx] = f2bf_rne(aw1[idx]);
        } else if (idx < 262144) {
            int k2 = idx - 131072;
            w2hi[k2] = f2bf_rne(aw2[k2]);
        } else {
            int k2 = idx - 262144;          // k2 = (h*64+d)*64 + p
            int p = k2 & 63; int hd = k2 >> 6;
            int h = hd >> 6; int d = hd & 63;
            rw2hi[k2] = f2bf_rne(pw2[(size_t)p * INNER + h * DH + d]);
        }
    }
}

// ---- K0b: transpose+split 512x512 weights (full hi/lo, 3-pass GEMMs keep precision).
__global__ __launch_bounds__(256) void k_split_T(const float* __restrict__ wq,
                                                 const float* __restrict__ wk,
                                                 const float* __restrict__ wv,
                                                 const float* __restrict__ wout,
                                                 u16* __restrict__ o0h, u16* __restrict__ o0l,
                                                 u16* __restrict__ o1h, u16* __restrict__ o1l,
                                                 u16* __restrict__ o2h, u16* __restrict__ o2l,
                                                 u16* __restrict__ o3h, u16* __restrict__ o3l)
{
    __shared__ float S[64][65];
    const int t = threadIdx.x;
    const int e0 = blockIdx.x * 64, c0 = blockIdx.y * 64;
    const float* src; u16* dh; u16* dl;
    switch (blockIdx.z) {
        case 0:  src = wq;   dh = o0h; dl = o0l; break;
        case 1:  src = wk;   dh = o1h; dl = o1l; break;
        case 2:  src = wv;   dh = o2h; dl = o2l; break;
        default: src = wout; dh = o3h; dl = o3l; break;
    }
    #pragma unroll
    for (int s = 0; s < 16; ++s) {
        int v = s * 256 + t; int r = v >> 6, c = v & 63;
        S[r][c] = src[(size_t)(e0 + r) * 512 + c0 + c];
    }
    __syncthreads();
    #pragma unroll
    for (int s = 0; s < 16; ++s) {
        int v = s * 256 + t; int c = v >> 6, e = v & 63;
        u16 hi, lo; split2(S[e][c], hi, lo);
        size_t off = (size_t)(c0 + c) * 512 + e0 + e;
        dh[off] = hi; dl[off] = lo;
    }
}

// ---- K1: MFMA projection GEMM (unchanged, verified). D = q@wq + (-k)@wk, V = v@wv.
__global__ __launch_bounds__(256) void k_projM(const u16* __restrict__ qhi, const u16* __restrict__ qlo,
                                               const u16* __restrict__ khi, const u16* __restrict__ klo,
                                               const u16* __restrict__ vhi, const u16* __restrict__ vlo,
                                               const u16* __restrict__ wqh, const u16* __restrict__ wql,
                                               const u16* __restrict__ wkh, const u16* __restrict__ wkl,
                                               const u16* __restrict__ wvh, const u16* __restrict__ wvl,
                                               float* __restrict__ Dws, float* __restrict__ Vws)
{
    __shared__ u16 S[12][64 * 40];
    const int t = threadIdx.x, l = t & 63, w = t >> 6;
    const int lm = l & 15, lg = (l >> 4) * 8;
    const int g0 = blockIdx.x * 64, c0 = blockIdx.y * 64;
    const int sr = t >> 2, sc = (t & 3) * 8;

    f32x4 accD[4] = {{0,0,0,0},{0,0,0,0},{0,0,0,0},{0,0,0,0}};
    f32x4 accV[4] = {{0,0,0,0},{0,0,0,0},{0,0,0,0},{0,0,0,0}};

    for (int ks = 0; ks < 16; ++ks) {
        const int k0 = ks * 32;
        if (ks) __syncthreads();
        #define STG(p, base, rb) \
            *(uint4*)&S[p][sr * 40 + sc] = *(const uint4*)&(base)[(size_t)((rb) + sr) * 512 + k0 + sc];
        STG(0, qhi, g0) STG(1, qlo, g0) STG(2, khi, g0) STG(3, klo, g0)
        STG(4, vhi, g0) STG(5, vlo, g0)
        STG(6, wqh, c0) STG(7, wql, c0) STG(8, wkh, c0) STG(9, wkl, c0)
        STG(10, wvh, c0) STG(11, wvl, c0)
        #undef STG
        __syncthreads();

        const int ao = (w * 16 + lm) * 40 + lg;
        bf16x8 aqh = *(const bf16x8*)&S[0][ao];
        bf16x8 aql = *(const bf16x8*)&S[1][ao];
        bf16x8 akh = *(const bf16x8*)&S[2][ao];
        bf16x8 akl = *(const bf16x8*)&S[3][ao];
        bf16x8 avh = *(const bf16x8*)&S[4][ao];
        bf16x8 avl = *(const bf16x8*)&S[5][ao];
        #pragma unroll
        for (int ct = 0; ct < 4; ++ct) {
            const int bo = (ct * 16 + lm) * 40 + lg;
            bf16x8 bqh = *(const bf16x8*)&S[6][bo];
            bf16x8 bql = *(const bf16x8*)&S[7][bo];
            bf16x8 bkh = *(const bf16x8*)&S[8][bo];
            bf16x8 bkl = *(const bf16x8*)&S[9][bo];
            bf16x8 bvh = *(const bf16x8*)&S[10][bo];
            bf16x8 bvl = *(const bf16x8*)&S[11][bo];
            accD[ct] = __builtin_amdgcn_mfma_f32_16x16x32_bf16(aqh, bqh, accD[ct], 0, 0, 0);
            accD[ct] = __builtin_amdgcn_mfma_f32_16x16x32_bf16(aql, bqh, accD[ct], 0, 0, 0);
            accD[ct] = __builtin_amdgcn_mfma_f32_16x16x32_bf16(aqh, bql, accD[ct], 0, 0, 0);
            accD[ct] = __builtin_amdgcn_mfma_f32_16x16x32_bf16(akh, bkh, accD[ct], 0, 0, 0);
            accD[ct] = __builtin_amdgcn_mfma_f32_16x16x32_bf16(akl, bkh, accD[ct], 0, 0, 0);
            accD[ct] = __builtin_amdgcn_mfma_f32_16x16x32_bf16(akh, bkl, accD[ct], 0, 0, 0);
            accV[ct] = __builtin_amdgcn_mfma_f32_16x16x32_bf16(avh, bvh, accV[ct], 0, 0, 0);
            accV[ct] = __builtin_amdgcn_mfma_f32_16x16x32_bf16(avl, bvh, accV[ct], 0, 0, 0);
            accV[ct] = __builtin_amdgcn_mfma_f32_16x16x32_bf16(avh, bvl, accV[ct], 0, 0, 0);
        }
    }

    const int b = blockIdx.x >> 4;
    const int h = blockIdx.y;
    #pragma unroll
    for (int ct = 0; ct < 4; ++ct) {
        #pragma unroll
        for (int r = 0; r < 4; ++r) {
            int g = g0 + w * 16 + (l >> 4) * 4 + r;
            int i = g & 1023;
            size_t off = (((size_t)(b * HH + h)) * NPT + i) * DH + ct * 16 + lm;
            Dws[off] = accD[ct][r];
            Vws[off] = accV[ct][r];
        }
    }
}

// ---- K2: KNN — one wave per (b,i), no barriers, all-register top-16.
// Lane l owns j = l*16..l*16+15. Lexicographic (d2, j) shfl reduce == stable top_k.
__global__ __launch_bounds__(256) void k_knn(const float* __restrict__ canonical, int* __restrict__ nbr)
{
    const int t = threadIdx.x, l = t & 63, w = t >> 6;
    const int i = blockIdx.x * 4 + w;
    const int b = blockIdx.y;
    const float* cb = canonical + (size_t)b * NPT * 3;
    const float qx = cb[i*3+0], qy = cb[i*3+1], qz = cb[i*3+2];
    float d2v[16];
    #pragma unroll
    for (int k = 0; k < 16; ++k) {
        int j = l * 16 + k;
        float dx = __fsub_rn(cb[j*3+0], qx);
        float dy = __fsub_rn(cb[j*3+1], qy);
        float dz = __fsub_rn(cb[j*3+2], qz);
        d2v[k] = __fadd_rn(__fadd_rn(__fmul_rn(dx,dx), __fmul_rn(dy,dy)), __fmul_rn(dz,dz));
    }
    unsigned alive = 0xFFFFu;
    int* out = nbr + ((size_t)b * NPT + i) * KNN;
    for (int sel = 0; sel < KNN; ++sel) {
        float bv = __builtin_inff(); int bk = 16;
        #pragma unroll
        for (int k = 0; k < 16; ++k) {
            float v = ((alive >> k) & 1u) ? d2v[k] : __builtin_inff();
            if (v < bv) { bv = v; bk = k; }   // ascending k: ties keep lowest j
        }
        int bj = l * 16 + bk;
        #pragma unroll
        for (int m = 32; m >= 1; m >>= 1) {
            float ov = __shfl_xor(bv, m, 64);
            int   oj = __shfl_xor(bj, m, 64);
            if (ov < bv || (ov == bv && oj < bj)) { bv = ov; bj = oj; }
        }
        if (l == 0) out[sel] = bj;
        if ((bj >> 4) == l) alive &= ~(1u << (bj & 15));
    }
}

// ---- K3: MFMA attn kernel. 2-pass (activation-split x rne-weights), gather prefetch.
__global__ __launch_bounds__(256) void k_attn(const float* __restrict__ Dws,
                                              const float* __restrict__ Vws,
                                              const float* __restrict__ canonical,
                                              const int* __restrict__ nbr,
                                              const float* __restrict__ pw1,
                                              const float* __restrict__ pb1,
                                              const float* __restrict__ pb2,
                                              const float* __restrict__ ab1,
                                              const float* __restrict__ ab2,
                                              const u16* __restrict__ w1hi,
                                              const u16* __restrict__ w2hi,
                                              const u16* __restrict__ rw2hi,
                                              u16* __restrict__ vvb,
                                              float* __restrict__ attn)
{
    const int it = blockIdx.x, h = blockIdx.y, b = blockIdx.z, t = threadIdx.x;
    const int l = t & 63, w = t >> 6;
    const int lm = l & 15, lg = (l >> 4) * 8;
    const int dd = w * 16 + lm;

    __shared__ u16 h1hi[16 * 72], h1lo[16 * 72];
    __shared__ u16 Xhi[16 * 72],  Xlo[16 * 72];
    __shared__ u16 Hhi[16 * 264], Hlo[16 * 264];
    __shared__ u16 rw2s[64 * 72];          // rpe B-frags in LDS (saves 16 VGPR)
    __shared__ float pw1s[3 * POSH];
    __shared__ float pb1s[POSH];
    __shared__ float rel_all[8][KNN][3];
    __shared__ int nbrrow[KNN];

    // rne weight fragments (hi only): w1 32 VGPR + w2 32 VGPR
    bf16x8 w1f[8], w2f[8];
    float b1v[4];
    #pragma unroll
    for (int q = 0; q < 4; ++q) {
        int e = (w * 4 + q) * 16 + lm;
        b1v[q] = ab1[h * AINNER + e];
        #pragma unroll
        for (int kc = 0; kc < 2; ++kc)
            w1f[q*2+kc] = *(const bf16x8*)&w1hi[((size_t)(h * AINNER + e)) * DH + kc * 32 + lg];
    }
    const float b2v  = ab2[h * DH + dd];
    const float pb2v = pb2[h * DH + dd];
    #pragma unroll
    for (int kc = 0; kc < 8; ++kc)
        w2f[kc] = *(const bf16x8*)&w2hi[((size_t)(h * DH + dd)) * AINNER + kc * 32 + lg];

    for (int v = t; v < 64 * 64; v += 256) {
        int d = v >> 6, p = v & 63;
        rw2s[d * 72 + p] = rw2hi[(h * DH + d) * POSH + p];
    }
    if (t < 192) pw1s[t] = pw1[t];
    if (t < 64)  pb1s[t] = pb1[t];
    if (t < KNN) nbrrow[t] = nbr[((size_t)b * NPT + h * 128 + it) * KNN + t];
    if (t < 128) {
        int ti = t >> 4, jj = t & 15;
        int i2 = it * 8 + ti;
        int nv2 = nbr[((size_t)b * NPT + i2) * KNN + jj];
        const float* cn = canonical + ((size_t)b * NPT + nv2) * 3;
        const float* ci = canonical + ((size_t)b * NPT + i2) * 3;
        rel_all[ti][jj][0] = cn[0] - ci[0];
        rel_all[ti][jj][1] = cn[1] - ci[1];
        rel_all[ti][jj][2] = cn[2] - ci[2];
    }
    __syncthreads();

    // gather prefetch: issued one ti ahead, consumed in phase B
    float dvp[4], vwp[4];
    auto gather = [&](int tt) {
        #pragma unroll
        for (int r = 0; r < 4; ++r) {
            int j = (l >> 4) * 4 + r;
            int nv = nbrrow[2 * tt + (j >> 3)];
            size_t off = (((size_t)b * HH + (nv >> 7)) * NPT + (nv & 127) * 8 + (j & 7)) * DH + dd;
            dvp[r] = Dws[off];
            vwp[r] = Vws[off];
        }
    };
    gather(0);

    for (int ti = 0; ti < 8; ++ti) {
        const int i = it * 8 + ti;
        // ---- Phase A: h1 = relu(rel@pw1 + pb1), trunc-split (activation side)
        #pragma unroll
        for (int r = 0; r < 4; ++r) {
            int v = r * 256 + t; int j = v >> 6; int p = v & 63;
            float a = pb1s[p];
            a = fmaf(rel_all[ti][j][0], pw1s[p], a);
            a = fmaf(rel_all[ti][j][1], pw1s[64 + p], a);
            a = fmaf(rel_all[ti][j][2], pw1s[128 + p], a);
            a = fmaxf(a, 0.0f);
            u16 hi, lo; split2(a, hi, lo);
            h1hi[j * 72 + p] = hi;
            h1lo[j * 72 + p] = lo;
        }
        __syncthreads();
        // ---- Phase B: rpe MFMA (2-pass) + consume prefetched gather + X/vv, then prefetch ti+1
        {
            f32x4 racc = {0.f, 0.f, 0.f, 0.f};
            #pragma unroll
            for (int kc = 0; kc < 2; ++kc) {
                bf16x8 ah = *(const bf16x8*)&h1hi[lm * 72 + kc * 32 + lg];
                bf16x8 al = *(const bf16x8*)&h1lo[lm * 72 + kc * 32 + lg];
                bf16x8 rb = *(const bf16x8*)&rw2s[dd * 72 + kc * 32 + lg];
                racc = __builtin_amdgcn_mfma_f32_16x16x32_bf16(ah, rb, racc, 0, 0, 0);
                racc = __builtin_amdgcn_mfma_f32_16x16x32_bf16(al, rb, racc, 0, 0, 0);
            }
            u16* vvrow = vvb + (((size_t)(b * HH + h) * NPT + i) * KNN) * DH + dd;
            #pragma unroll
            for (int r = 0; r < 4; ++r) {
                int j = (l >> 4) * 4 + r;
                float rp = racc[r] + pb2v;
                float x = dvp[r] + rp;
                u16 hi, lo; split2(x, hi, lo);
                Xhi[j * 72 + dd] = hi;
                Xlo[j * 72 + dd] = lo;
                vvrow[j * DH] = f2bf_rne(vwp[r] + rp);
            }
            if (ti < 7) gather(ti + 1);
        }
        __syncthreads();
        // ---- Phase C: MLP1 (2-pass): H = relu(X @ W1^T + b1)
        {
            f32x4 acc1[4] = {{0,0,0,0},{0,0,0,0},{0,0,0,0},{0,0,0,0}};
            #pragma unroll
            for (int kc = 0; kc < 2; ++kc) {
                bf16x8 ah = *(const bf16x8*)&Xhi[lm * 72 + kc * 32 + lg];
                bf16x8 al = *(const bf16x8*)&Xlo[lm * 72 + kc * 32 + lg];
                #pragma unroll
                for (int q = 0; q < 4; ++q) {
                    acc1[q] = __builtin_amdgcn_mfma_f32_16x16x32_bf16(ah, w1f[q*2+kc], acc1[q], 0, 0, 0);
                    acc1[q] = __builtin_amdgcn_mfma_f32_16x16x32_bf16(al, w1f[q*2+kc], acc1[q], 0, 0, 0);
                }
            }
            #pragma unroll
            for (int q = 0; q < 4; ++q) {
                int ee = (w * 4 + q) * 16 + lm;
                #pragma unroll
                for (int r = 0; r < 4; ++r) {
                    int jj = (l >> 4) * 4 + r;
                    float v2 = fmaxf(acc1[q][r] + b1v[q], 0.0f);
                    u16 hi, lo; split2(v2, hi, lo);
                    Hhi[jj * 264 + ee] = hi;
                    Hlo[jj * 264 + ee] = lo;
                }
            }
        }
        __syncthreads();
        // ---- Phase D: MLP2 (2-pass) + in-wave softmax + attn store (no trailing barrier)
        {
            f32x4 acc2[4] = {{0,0,0,0},{0,0,0,0},{0,0,0,0},{0,0,0,0}};
            #pragma unroll
            for (int kc = 0; kc < 8; ++kc) {
                bf16x8 ah = *(const bf16x8*)&Hhi[lm * 264 + kc * 32 + lg];
                bf16x8 al = *(const bf16x8*)&Hlo[lm * 264 + kc * 32 + lg];
                int p = kc & 3;
                acc2[p] = __builtin_amdgcn_mfma_f32_16x16x32_bf16(ah, w2f[kc], acc2[p], 0, 0, 0);
                acc2[p] = __builtin_amdgcn_mfma_f32_16x16x32_bf16(al, w2f[kc], acc2[p], 0, 0, 0);
            }
            float sim[4];
            #pragma unroll
            for (int r = 0; r < 4; ++r)
                sim[r] = ((acc2[0][r] + acc2[1][r]) + (acc2[2][r] + acc2[3][r])) + b2v;
            float m = fmaxf(fmaxf(sim[0], sim[1]), fmaxf(sim[2], sim[3]));
            m = fmaxf(m, __shfl_xor(m, 16, 64));
            m = fmaxf(m, __shfl_xor(m, 32, 64));
            float ex[4], s = 0.0f;
            #pragma unroll
            for (int r = 0; r < 4; ++r) { ex[r] = __expf(sim[r] - m); s += ex[r]; }
            s += __shfl_xor(s, 16, 64);
            s += __shfl_xor(s, 32, 64);
            float inv = 1.0f / s;
            float* ao = attn + (((size_t)(b * HH + h) * NPT + i) * KNN) * DH + dd;
            #pragma unroll
            for (int r = 0; r < 4; ++r)
                ao[((l >> 4) * 4 + r) * DH] = ex[r] * inv;
        }
    }
}

// ---- K4: partial sums of attn^2 over i (128-chunk per block) -> npart
__global__ __launch_bounds__(256) void k_norm1(const float* __restrict__ attn, float* __restrict__ npart)
{
    const int j = blockIdx.x, h = blockIdx.y, bz = blockIdx.z;
    const int b = bz >> 3, ic = bz & 7;
    const int t = threadIdx.x, d = t & 63, q4 = t >> 6;
    const float* base = attn + ((size_t)(b * HH + h) * NPT) * KNN * DH + j * DH + d;
    float acc = 0.0f;
    for (int r = 0; r < 32; ++r) {
        int i = ic * 128 + q4 + r * 4;
        float a = base[(size_t)i * KNN * DH];
        acc = fmaf(a, a, acc);
    }
    __shared__ float red[256];
    red[t] = acc;
    __syncthreads();
    if (q4 == 0) {
        float s = red[d] + red[64 + d] + red[128 + d] + red[192 + d];
        npart[(((size_t)(b * HH + h) * KNN + j) * DH + d) + 16384 * ic] = s;
    }
}

// ---- K5: agg = sum_j (attn/max(nrm,1e-12)) * vv (norm2 fused: reduce npart here)
__global__ __launch_bounds__(256) void k_agg(const float* __restrict__ attn,
                                             const float* __restrict__ npart,
                                             const u16* __restrict__ vvb,
                                             u16* __restrict__ agghi,
                                             u16* __restrict__ agglo)
{
    const int it = blockIdx.x, h = blockIdx.y, b = blockIdx.z, t = threadIdx.x;
    const int d = t & 63, si = t >> 6;
    const int i = it * 4 + si;
    __shared__ float rn[KNN * DH];
    const size_t nb = (size_t)(b * HH + h) * (KNN * DH);
    for (int v = t; v < KNN * DH; v += 256) {
        float s = 0.0f;
        #pragma unroll
        for (int ic = 0; ic < 8; ++ic) s += npart[nb + v + 16384 * ic];
        rn[v] = 1.0f / fmaxf(sqrtf(s), 1e-12f);
    }
    __syncthreads();
    const float* ab = attn + (((size_t)(b * HH + h) * NPT + i) * KNN) * DH + d;
    const u16*   vb = vvb  + (((size_t)(b * HH + h) * NPT + i) * KNN) * DH + d;
    float acc = 0.0f;
    #pragma unroll
    for (int j = 0; j < KNN; ++j) {
        float a  = ab[j * DH];
        float vv = bf2f(vb[j * DH]);
        acc = fmaf(a * rn[j * DH + d], vv, acc);
    }
    size_t off = ((size_t)b * NPT + i) * INNER + h * DH + d;
    u16 hi, lo; split2(acc, hi, lo);
    agghi[off] = hi;
    agglo[off] = lo;
}

// ---- K6: MFMA out GEMM (unchanged, verified): out = agg @ w_out + b_out.
__global__ __launch_bounds__(256) void k_outM(const u16* __restrict__ agghi, const u16* __restrict__ agglo,
                                              const u16* __restrict__ wth, const u16* __restrict__ wtl,
                                              const float* __restrict__ bout,
                                              float* __restrict__ outp)
{
    __shared__ u16 S[4][64 * 40];
    const int t = threadIdx.x, l = t & 63, w = t >> 6;
    const int lm = l & 15, lg = (l >> 4) * 8;
    const int g0 = blockIdx.x * 64, c0 = blockIdx.y * 64;
    const int sr = t >> 2, sc = (t & 3) * 8;

    f32x4 acc[4] = {{0,0,0,0},{0,0,0,0},{0,0,0,0},{0,0,0,0}};
    float bv4[4];
    #pragma unroll
    for (int ct = 0; ct < 4; ++ct) bv4[ct] = bout[c0 + ct * 16 + lm];

    for (int ks = 0; ks < 16; ++ks) {
        const int k0 = ks * 32;
        if (ks) __syncthreads();
        *(uint4*)&S[0][sr * 40 + sc] = *(const uint4*)&agghi[(size_t)(g0 + sr) * 512 + k0 + sc];
        *(uint4*)&S[1][sr * 40 + sc] = *(const uint4*)&agglo[(size_t)(g0 + sr) * 512 + k0 + sc];
        *(uint4*)&S[2][sr * 40 + sc] = *(const uint4*)&wth[(size_t)(c0 + sr) * 512 + k0 + sc];
        *(uint4*)&S[3][sr * 40 + sc] = *(const uint4*)&wtl[(size_t)(c0 + sr) * 512 + k0 + sc];
        __syncthreads();

        const int ao = (w * 16 + lm) * 40 + lg;
        bf16x8 ah = *(const bf16x8*)&S[0][ao];
        bf16x8 al = *(const bf16x8*)&S[1][ao];
        #pragma unroll
        for (int ct = 0; ct < 4; ++ct) {
            const int bo = (ct * 16 + lm) * 40 + lg;
            bf16x8 bh = *(const bf16x8*)&S[2][bo];
            bf16x8 bl = *(const bf16x8*)&S[3][bo];
            acc[ct] = __builtin_amdgcn_mfma_f32_16x16x32_bf16(ah, bh, acc[ct], 0, 0, 0);
            acc[ct] = __builtin_amdgcn_mfma_f32_16x16x32_bf16(al, bh, acc[ct], 0, 0, 0);
            acc[ct] = __builtin_amdgcn_mfma_f32_16x16x32_bf16(ah, bl, acc[ct], 0, 0, 0);
        }
    }
    #pragma unroll
    for (int ct = 0; ct < 4; ++ct) {
        #pragma unroll
        for (int r = 0; r < 4; ++r) {
            int g = g0 + w * 16 + (l >> 4) * 4 + r;
            outp[(size_t)g * 512 + c0 + ct * 16 + lm] = acc[ct][r] + bv4[ct];
        }
    }
}

extern "C" void kernel_launch(void* const* d_in, const int* in_sizes, int n_in,
                              void* d_out, int out_size, void* d_ws, size_t ws_size,
                              hipStream_t stream) {
    const float* query     = (const float*)d_in[0];
    const float* key_in    = (const float*)d_in[1];
    const float* value     = (const float*)d_in[2];
    const float* canonical = (const float*)d_in[3];
    const float* wq   = (const float*)d_in[4];
    const float* wk   = (const float*)d_in[5];
    const float* wv   = (const float*)d_in[6];
    const float* wout = (const float*)d_in[7];
    const float* bout = (const float*)d_in[8];
    const float* pw1  = (const float*)d_in[9];
    const float* pb1  = (const float*)d_in[10];
    const float* pw2  = (const float*)d_in[11];
    const float* pb2  = (const float*)d_in[12];
    const float* aw1  = (const float*)d_in[13];
    const float* ab1  = (const float*)d_in[14];
    const float* aw2  = (const float*)d_in[15];
    const float* ab2  = (const float*)d_in[16];

    float* ws    = (float*)d_ws;
    float* Dws   = ws;                    // 1,048,576 f
    float* Vws   = ws + 1048576;          // 1,048,576 f
    float* aggp  = ws + 2097152;          // 1,048,576 f (agg hi/lo u16 planes)
    float* npart = ws + 3162112;          // 131,072 f
    int*   nbr   = (int*)(ws + 3293184);  // 32,768 i32
    float* attn  = ws + 3325952;          // 16,777,216 f

    u16* agghi = (u16*)aggp;              // 1,048,576 u16
    u16* agglo = agghi + 1048576;

    // input/weight planes alias the attn region (consumed by projM before attn written)
    u16* pl   = (u16*)attn;
    u16* qhi  = pl;                u16* qlo  = pl + 1048576;
    u16* khi  = pl + 2097152;      u16* klo  = pl + 3145728;
    u16* vhi  = pl + 4194304;      u16* vlo  = pl + 5242880;
    u16* wqTh = pl + 6291456;      u16* wqTl = pl + 6553600;
    u16* wkTh = pl + 6815744;      u16* wkTl = pl + 7077888;
    u16* wvTh = pl + 7340032;      u16* wvTl = pl + 7602176;

    u16* u16b  = (u16*)(ws + 20103168);
    u16* w1hi  = u16b;                    // 131,072 u16
    u16* w2hi  = u16b + 262144;           // 131,072 u16 (keeps old offsets)
    u16* rw2hi = u16b + 524288;           // 32,768 u16
    u16* vvb   = u16b + 589824;           // 16,777,216 u16
    u16* wouTh = u16b + 17367040;
    u16* wouTl = u16b + 17629184;         // end ~116 MB total ws

    k_pre<<<4224, 256, 0, stream>>>(query, key_in, value, aw1, aw2, pw2,
                                    qhi, qlo, khi, klo, vhi, vlo, w1hi, w2hi, rw2hi);
    k_split_T<<<dim3(8, 8, 4), 256, 0, stream>>>(wq, wk, wv, wout,
                                                 wqTh, wqTl, wkTh, wkTl, wvTh, wvTl, wouTh, wouTl);
    k_projM<<<dim3(32, 8), 256, 0, stream>>>(qhi, qlo, khi, klo, vhi, vlo,
                                             wqTh, wqTl, wkTh, wkTl, wvTh, wvTl, Dws, Vws);
    k_knn<<<dim3(256, BS), 256, 0, stream>>>(canonical, nbr);
    k_attn<<<dim3(128, HH, BS), 256, 0, stream>>>(Dws, Vws, canonical, nbr, pw1, pb1, pb2,
                                                  ab1, ab2, w1hi, w2hi, rw2hi, vvb, attn);
    k_norm1<<<dim3(KNN, HH, BS * 8), 256, 0, stream>>>(attn, npart);
    k_agg<<<dim3(256, HH, BS), 256, 0, stream>>>(attn, npart, vvb, agghi, agglo);
    k_outM<<<dim3(32, 8), 256, 0, stream>>>(agghi, agglo, wouTh, wouTl, bout, (float*)d_out);
}

// Round 8
// 171.402 us; speedup vs baseline: 5.4344x; 1.1390x over previous
//
#include <hip/hip_runtime.h>

// MultiHeadVectorAttention — round 8: X single-rne (MLP1 1-pass), bf16 attn buffer,
// launch_bounds(256,3) on k_attn. Everything else as round 7 (verified).
// bs=2, n=1024, H=8, DH=64, K=16, EMB=INNER=512, AINNER=256, POSH=64.

#define BS 2
#define NPT 1024
#define HH 8
#define DH 64
#define KNN 16
#define EMB 512
#define INNER 512
#define AINNER 256
#define POSH 64

typedef unsigned short u16;
typedef unsigned int u32;
typedef __attribute__((ext_vector_type(8))) short bf16x8;
typedef __attribute__((ext_vector_type(4))) float f32x4;

__device__ __forceinline__ float bf2f(u16 b) { union { u32 u; float f; } v; v.u = ((u32)b) << 16; return v.f; }
__device__ __forceinline__ u16 f2bf_rne(float f) {
    u32 x = __float_as_uint(f);
    u32 r = x + 0x7fffu + ((x >> 16) & 1u);
    return (u16)(r >> 16);
}
// truncation split: hi = trunc-bf16(f), lo = rne-bf16(f - hi). total rel err ~2^-17.
__device__ __forceinline__ void split2(float f, u16& hi, u16& lo) {
    u32 bits = __float_as_uint(f);
    hi = (u16)(bits >> 16);
    float resid = f - __uint_as_float(bits & 0xffff0000u);
    lo = (u16)(__float_as_uint(resid) >> 16);
}

// ---- K0a: fused: split q/k(neg)/v into hi/lo planes  +  rne-quantize attn weights.
__global__ __launch_bounds__(256) void k_pre(const float* __restrict__ query,
                                             const float* __restrict__ key_in,
                                             const float* __restrict__ value,
                                             const float* __restrict__ aw1,
                                             const float* __restrict__ aw2,
                                             const float* __restrict__ pw2,
                                             u16* __restrict__ qhi, u16* __restrict__ qlo,
                                             u16* __restrict__ khi, u16* __restrict__ klo,
                                             u16* __restrict__ vhi, u16* __restrict__ vlo,
                                             u16* __restrict__ w1hi, u16* __restrict__ w2hi,
                                             u16* __restrict__ rw2hi)
{
    const int bx = blockIdx.x, t = threadIdx.x;
    if (bx < 3072) {
        const int m = bx >> 10;
        const int v = (((bx & 1023) * 256) + t) * 4;
        const float* src; u16* dh; u16* dl;
        switch (m) {
            case 0:  src = query;  dh = qhi; dl = qlo; break;
            case 1:  src = key_in; dh = khi; dl = klo; break;
            default: src = value;  dh = vhi; dl = vlo; break;
        }
        float4 f = *(const float4*)&src[v];
        if (m == 1) { f.x = -f.x; f.y = -f.y; f.z = -f.z; f.w = -f.w; }
        ushort4 h4, l4;
        split2(f.x, h4.x, l4.x); split2(f.y, h4.y, l4.y);
        split2(f.z, h4.z, l4.z); split2(f.w, h4.w, l4.w);
        *(ushort4*)&dh[v] = h4;
        *(ushort4*)&dl[v] = l4;
    } else {
        int idx = (bx - 3072) * 256 + t;
        if (idx < 131072) {
            w1hi[idx] = f2bf_rne(aw1[idx]);
        } else if (idx < 262144) {
            int k2 = idx - 131072;
            w2hi[k2] = f2bf_rne(aw2[k2]);
        } else {
            int k2 = idx - 262144;          // k2 = (h*64+d)*64 + p
            int p = k2 & 63; int hd = k2 >> 6;
            int h = hd >> 6; int d = hd & 63;
            rw2hi[k2] = f2bf_rne(pw2[(size_t)p * INNER + h * DH + d]);
        }
    }
}

// ---- K0b: transpose+split 512x512 weights (full hi/lo for 3-pass GEMMs).
__global__ __launch_bounds__(256) void k_split_T(const float* __restrict__ wq,
                                                 const float* __restrict__ wk,
                                                 const float* __restrict__ wv,
                                                 const float* __restrict__ wout,
                                                 u16* __restrict__ o0h, u16* __restrict__ o0l,
                                                 u16* __restrict__ o1h, u16* __restrict__ o1l,
                                                 u16* __restrict__ o2h, u16* __restrict__ o2l,
                                                 u16* __restrict__ o3h, u16* __restrict__ o3l)
{
    __shared__ float S[64][65];
    const int t = threadIdx.x;
    const int e0 = blockIdx.x * 64, c0 = blockIdx.y * 64;
    const float* src; u16* dh; u16* dl;
    switch (blockIdx.z) {
        case 0:  src = wq;   dh = o0h; dl = o0l; break;
        case 1:  src = wk;   dh = o1h; dl = o1l; break;
        case 2:  src = wv;   dh = o2h; dl = o2l; break;
        default: src = wout; dh = o3h; dl = o3l; break;
    }
    #pragma unroll
    for (int s = 0; s < 16; ++s) {
        int v = s * 256 + t; int r = v >> 6, c = v & 63;
        S[r][c] = src[(size_t)(e0 + r) * 512 + c0 + c];
    }
    __syncthreads();
    #pragma unroll
    for (int s = 0; s < 16; ++s) {
        int v = s * 256 + t; int c = v >> 6, e = v & 63;
        u16 hi, lo; split2(S[e][c], hi, lo);
        size_t off = (size_t)(c0 + c) * 512 + e0 + e;
        dh[off] = hi; dl[off] = lo;
    }
}

// ---- K1: MFMA projection GEMM (verified). D = q@wq + (-k)@wk, V = v@wv.
__global__ __launch_bounds__(256) void k_projM(const u16* __restrict__ qhi, const u16* __restrict__ qlo,
                                               const u16* __restrict__ khi, const u16* __restrict__ klo,
                                               const u16* __restrict__ vhi, const u16* __restrict__ vlo,
                                               const u16* __restrict__ wqh, const u16* __restrict__ wql,
                                               const u16* __restrict__ wkh, const u16* __restrict__ wkl,
                                               const u16* __restrict__ wvh, const u16* __restrict__ wvl,
                                               float* __restrict__ Dws, float* __restrict__ Vws)
{
    __shared__ u16 S[12][64 * 40];
    const int t = threadIdx.x, l = t & 63, w = t >> 6;
    const int lm = l & 15, lg = (l >> 4) * 8;
    const int g0 = blockIdx.x * 64, c0 = blockIdx.y * 64;
    const int sr = t >> 2, sc = (t & 3) * 8;

    f32x4 accD[4] = {{0,0,0,0},{0,0,0,0},{0,0,0,0},{0,0,0,0}};
    f32x4 accV[4] = {{0,0,0,0},{0,0,0,0},{0,0,0,0},{0,0,0,0}};

    for (int ks = 0; ks < 16; ++ks) {
        const int k0 = ks * 32;
        if (ks) __syncthreads();
        #define STG(p, base, rb) \
            *(uint4*)&S[p][sr * 40 + sc] = *(const uint4*)&(base)[(size_t)((rb) + sr) * 512 + k0 + sc];
        STG(0, qhi, g0) STG(1, qlo, g0) STG(2, khi, g0) STG(3, klo, g0)
        STG(4, vhi, g0) STG(5, vlo, g0)
        STG(6, wqh, c0) STG(7, wql, c0) STG(8, wkh, c0) STG(9, wkl, c0)
        STG(10, wvh, c0) STG(11, wvl, c0)
        #undef STG
        __syncthreads();

        const int ao = (w * 16 + lm) * 40 + lg;
        bf16x8 aqh = *(const bf16x8*)&S[0][ao];
        bf16x8 aql = *(const bf16x8*)&S[1][ao];
        bf16x8 akh = *(const bf16x8*)&S[2][ao];
        bf16x8 akl = *(const bf16x8*)&S[3][ao];
        bf16x8 avh = *(const bf16x8*)&S[4][ao];
        bf16x8 avl = *(const bf16x8*)&S[5][ao];
        #pragma unroll
        for (int ct = 0; ct < 4; ++ct) {
            const int bo = (ct * 16 + lm) * 40 + lg;
            bf16x8 bqh = *(const bf16x8*)&S[6][bo];
            bf16x8 bql = *(const bf16x8*)&S[7][bo];
            bf16x8 bkh = *(const bf16x8*)&S[8][bo];
            bf16x8 bkl = *(const bf16x8*)&S[9][bo];
            bf16x8 bvh = *(const bf16x8*)&S[10][bo];
            bf16x8 bvl = *(const bf16x8*)&S[11][bo];
            accD[ct] = __builtin_amdgcn_mfma_f32_16x16x32_bf16(aqh, bqh, accD[ct], 0, 0, 0);
            accD[ct] = __builtin_amdgcn_mfma_f32_16x16x32_bf16(aql, bqh, accD[ct], 0, 0, 0);
            accD[ct] = __builtin_amdgcn_mfma_f32_16x16x32_bf16(aqh, bql, accD[ct], 0, 0, 0);
            accD[ct] = __builtin_amdgcn_mfma_f32_16x16x32_bf16(akh, bkh, accD[ct], 0, 0, 0);
            accD[ct] = __builtin_amdgcn_mfma_f32_16x16x32_bf16(akl, bkh, accD[ct], 0, 0, 0);
            accD[ct] = __builtin_amdgcn_mfma_f32_16x16x32_bf16(akh, bkl, accD[ct], 0, 0, 0);
            accV[ct] = __builtin_amdgcn_mfma_f32_16x16x32_bf16(avh, bvh, accV[ct], 0, 0, 0);
            accV[ct] = __builtin_amdgcn_mfma_f32_16x16x32_bf16(avl, bvh, accV[ct], 0, 0, 0);
            accV[ct] = __builtin_amdgcn_mfma_f32_16x16x32_bf16(avh, bvl, accV[ct], 0, 0, 0);
        }
    }

    const int b = blockIdx.x >> 4;
    const int h = blockIdx.y;
    #pragma unroll
    for (int ct = 0; ct < 4; ++ct) {
        #pragma unroll
        for (int r = 0; r < 4; ++r) {
            int g = g0 + w * 16 + (l >> 4) * 4 + r;
            int i = g & 1023;
            size_t off = (((size_t)(b * HH + h)) * NPT + i) * DH + ct * 16 + lm;
            Dws[off] = accD[ct][r];
            Vws[off] = accV[ct][r];
        }
    }
}

// ---- K2: KNN — one wave per (b,i), barrierless, stable top-16 (verified).
__global__ __launch_bounds__(256) void k_knn(const float* __restrict__ canonical, int* __restrict__ nbr)
{
    const int t = threadIdx.x, l = t & 63, w = t >> 6;
    const int i = blockIdx.x * 4 + w;
    const int b = blockIdx.y;
    const float* cb = canonical + (size_t)b * NPT * 3;
    const float qx = cb[i*3+0], qy = cb[i*3+1], qz = cb[i*3+2];
    float d2v[16];
    #pragma unroll
    for (int k = 0; k < 16; ++k) {
        int j = l * 16 + k;
        float dx = __fsub_rn(cb[j*3+0], qx);
        float dy = __fsub_rn(cb[j*3+1], qy);
        float dz = __fsub_rn(cb[j*3+2], qz);
        d2v[k] = __fadd_rn(__fadd_rn(__fmul_rn(dx,dx), __fmul_rn(dy,dy)), __fmul_rn(dz,dz));
    }
    unsigned alive = 0xFFFFu;
    int* out = nbr + ((size_t)b * NPT + i) * KNN;
    for (int sel = 0; sel < KNN; ++sel) {
        float bv = __builtin_inff(); int bk = 16;
        #pragma unroll
        for (int k = 0; k < 16; ++k) {
            float v = ((alive >> k) & 1u) ? d2v[k] : __builtin_inff();
            if (v < bv) { bv = v; bk = k; }
        }
        int bj = l * 16 + bk;
        #pragma unroll
        for (int m = 32; m >= 1; m >>= 1) {
            float ov = __shfl_xor(bv, m, 64);
            int   oj = __shfl_xor(bj, m, 64);
            if (ov < bv || (ov == bv && oj < bj)) { bv = ov; bj = oj; }
        }
        if (l == 0) out[sel] = bj;
        if ((bj >> 4) == l) alive &= ~(1u << (bj & 15));
    }
}

// ---- K3: MFMA attn kernel. X single-rne (MLP1 1-pass); bf16 attn out.
__global__ __launch_bounds__(256, 3) void k_attn(const float* __restrict__ Dws,
                                              const float* __restrict__ Vws,
                                              const float* __restrict__ canonical,
                                              const int* __restrict__ nbr,
                                              const float* __restrict__ pw1,
                                              const float* __restrict__ pb1,
                                              const float* __restrict__ pb2,
                                              const float* __restrict__ ab1,
                                              const float* __restrict__ ab2,
                                              const u16* __restrict__ w1hi,
                                              const u16* __restrict__ w2hi,
                                              const u16* __restrict__ rw2hi,
                                              u16* __restrict__ vvb,
                                              u16* __restrict__ attnb)
{
    const int it = blockIdx.x, h = blockIdx.y, b = blockIdx.z, t = threadIdx.x;
    const int l = t & 63, w = t >> 6;
    const int lm = l & 15, lg = (l >> 4) * 8;
    const int dd = w * 16 + lm;

    __shared__ u16 h1hi[16 * 72], h1lo[16 * 72];
    __shared__ u16 Xs[16 * 72];
    __shared__ u16 Hhi[16 * 264], Hlo[16 * 264];
    __shared__ u16 rw2s[64 * 72];
    __shared__ float pw1s[3 * POSH];
    __shared__ float pb1s[POSH];
    __shared__ float rel_all[8][KNN][3];
    __shared__ int nbrrow[KNN];

    bf16x8 w1f[8], w2f[8];
    float b1v[4];
    #pragma unroll
    for (int q = 0; q < 4; ++q) {
        int e = (w * 4 + q) * 16 + lm;
        b1v[q] = ab1[h * AINNER + e];
        #pragma unroll
        for (int kc = 0; kc < 2; ++kc)
            w1f[q*2+kc] = *(const bf16x8*)&w1hi[((size_t)(h * AINNER + e)) * DH + kc * 32 + lg];
    }
    const float b2v  = ab2[h * DH + dd];
    const float pb2v = pb2[h * DH + dd];
    #pragma unroll
    for (int kc = 0; kc < 8; ++kc)
        w2f[kc] = *(const bf16x8*)&w2hi[((size_t)(h * DH + dd)) * AINNER + kc * 32 + lg];

    for (int v = t; v < 64 * 64; v += 256) {
        int d = v >> 6, p = v & 63;
        rw2s[d * 72 + p] = rw2hi[(h * DH + d) * POSH + p];
    }
    if (t < 192) pw1s[t] = pw1[t];
    if (t < 64)  pb1s[t] = pb1[t];
    if (t < KNN) nbrrow[t] = nbr[((size_t)b * NPT + h * 128 + it) * KNN + t];
    if (t < 128) {
        int ti = t >> 4, jj = t & 15;
        int i2 = it * 8 + ti;
        int nv2 = nbr[((size_t)b * NPT + i2) * KNN + jj];
        const float* cn = canonical + ((size_t)b * NPT + nv2) * 3;
        const float* ci = canonical + ((size_t)b * NPT + i2) * 3;
        rel_all[ti][jj][0] = cn[0] - ci[0];
        rel_all[ti][jj][1] = cn[1] - ci[1];
        rel_all[ti][jj][2] = cn[2] - ci[2];
    }
    __syncthreads();

    float dvp[4], vwp[4];
    auto gather = [&](int tt) {
        #pragma unroll
        for (int r = 0; r < 4; ++r) {
            int j = (l >> 4) * 4 + r;
            int nv = nbrrow[2 * tt + (j >> 3)];
            size_t off = (((size_t)b * HH + (nv >> 7)) * NPT + (nv & 127) * 8 + (j & 7)) * DH + dd;
            dvp[r] = Dws[off];
            vwp[r] = Vws[off];
        }
    };
    gather(0);

    for (int ti = 0; ti < 8; ++ti) {
        const int i = it * 8 + ti;
        // ---- Phase A: h1 = relu(rel@pw1 + pb1), split (feeds 2-pass rpe)
        #pragma unroll
        for (int r = 0; r < 4; ++r) {
            int v = r * 256 + t; int j = v >> 6; int p = v & 63;
            float a = pb1s[p];
            a = fmaf(rel_all[ti][j][0], pw1s[p], a);
            a = fmaf(rel_all[ti][j][1], pw1s[64 + p], a);
            a = fmaf(rel_all[ti][j][2], pw1s[128 + p], a);
            a = fmaxf(a, 0.0f);
            u16 hi, lo; split2(a, hi, lo);
            h1hi[j * 72 + p] = hi;
            h1lo[j * 72 + p] = lo;
        }
        __syncthreads();
        // ---- Phase B: rpe MFMA (2-pass) + gather-consume + X rne + vv, prefetch ti+1
        {
            f32x4 racc = {0.f, 0.f, 0.f, 0.f};
            #pragma unroll
            for (int kc = 0; kc < 2; ++kc) {
                bf16x8 ah = *(const bf16x8*)&h1hi[lm * 72 + kc * 32 + lg];
                bf16x8 al = *(const bf16x8*)&h1lo[lm * 72 + kc * 32 + lg];
                bf16x8 rb = *(const bf16x8*)&rw2s[dd * 72 + kc * 32 + lg];
                racc = __builtin_amdgcn_mfma_f32_16x16x32_bf16(ah, rb, racc, 0, 0, 0);
                racc = __builtin_amdgcn_mfma_f32_16x16x32_bf16(al, rb, racc, 0, 0, 0);
            }
            u16* vvrow = vvb + (((size_t)(b * HH + h) * NPT + i) * KNN) * DH + dd;
            #pragma unroll
            for (int r = 0; r < 4; ++r) {
                int j = (l >> 4) * 4 + r;
                float rp = racc[r] + pb2v;
                Xs[j * 72 + dd] = f2bf_rne(dvp[r] + rp);
                vvrow[j * DH] = f2bf_rne(vwp[r] + rp);
            }
            if (ti < 7) gather(ti + 1);
        }
        __syncthreads();
        // ---- Phase C: MLP1 (1-pass): H = relu(X @ W1^T + b1), H split-stored
        {
            f32x4 acc1[4] = {{0,0,0,0},{0,0,0,0},{0,0,0,0},{0,0,0,0}};
            #pragma unroll
            for (int kc = 0; kc < 2; ++kc) {
                bf16x8 ah = *(const bf16x8*)&Xs[lm * 72 + kc * 32 + lg];
                #pragma unroll
                for (int q = 0; q < 4; ++q)
                    acc1[q] = __builtin_amdgcn_mfma_f32_16x16x32_bf16(ah, w1f[q*2+kc], acc1[q], 0, 0, 0);
            }
            #pragma unroll
            for (int q = 0; q < 4; ++q) {
                int ee = (w * 4 + q) * 16 + lm;
                #pragma unroll
                for (int r = 0; r < 4; ++r) {
                    int jj = (l >> 4) * 4 + r;
                    float v2 = fmaxf(acc1[q][r] + b1v[q], 0.0f);
                    u16 hi, lo; split2(v2, hi, lo);
                    Hhi[jj * 264 + ee] = hi;
                    Hlo[jj * 264 + ee] = lo;
                }
            }
        }
        __syncthreads();
        // ---- Phase D: MLP2 (2-pass) + in-wave softmax + bf16 attn store
        {
            f32x4 acc2[4] = {{0,0,0,0},{0,0,0,0},{0,0,0,0},{0,0,0,0}};
            #pragma unroll
            for (int kc = 0; kc < 8; ++kc) {
                bf16x8 ah = *(const bf16x8*)&Hhi[lm * 264 + kc * 32 + lg];
                bf16x8 al = *(const bf16x8*)&Hlo[lm * 264 + kc * 32 + lg];
                int p = kc & 3;
                acc2[p] = __builtin_amdgcn_mfma_f32_16x16x32_bf16(ah, w2f[kc], acc2[p], 0, 0, 0);
                acc2[p] = __builtin_amdgcn_mfma_f32_16x16x32_bf16(al, w2f[kc], acc2[p], 0, 0, 0);
            }
            float sim[4];
            #pragma unroll
            for (int r = 0; r < 4; ++r)
                sim[r] = ((acc2[0][r] + acc2[1][r]) + (acc2[2][r] + acc2[3][r])) + b2v;
            float m = fmaxf(fmaxf(sim[0], sim[1]), fmaxf(sim[2], sim[3]));
            m = fmaxf(m, __shfl_xor(m, 16, 64));
            m = fmaxf(m, __shfl_xor(m, 32, 64));
            float ex[4], s = 0.0f;
            #pragma unroll
            for (int r = 0; r < 4; ++r) { ex[r] = __expf(sim[r] - m); s += ex[r]; }
            s += __shfl_xor(s, 16, 64);
            s += __shfl_xor(s, 32, 64);
            float inv = 1.0f / s;
            u16* ao = attnb + (((size_t)(b * HH + h) * NPT + i) * KNN) * DH + dd;
            #pragma unroll
            for (int r = 0; r < 4; ++r)
                ao[((l >> 4) * 4 + r) * DH] = f2bf_rne(ex[r] * inv);
        }
    }
}

// ---- K4: partial sums of attn^2 over i (bf16 attn in)
__global__ __launch_bounds__(256) void k_norm1(const u16* __restrict__ attnb, float* __restrict__ npart)
{
    const int j = blockIdx.x, h = blockIdx.y, bz = blockIdx.z;
    const int b = bz >> 3, ic = bz & 7;
    const int t = threadIdx.x, d = t & 63, q4 = t >> 6;
    const u16* base = attnb + ((size_t)(b * HH + h) * NPT) * KNN * DH + j * DH + d;
    float acc = 0.0f;
    for (int r = 0; r < 32; ++r) {
        int i = ic * 128 + q4 + r * 4;
        float a = bf2f(base[(size_t)i * KNN * DH]);
        acc = fmaf(a, a, acc);
    }
    __shared__ float red[256];
    red[t] = acc;
    __syncthreads();
    if (q4 == 0) {
        float s = red[d] + red[64 + d] + red[128 + d] + red[192 + d];
        npart[(((size_t)(b * HH + h) * KNN + j) * DH + d) + 16384 * ic] = s;
    }
}

// ---- K5: agg = sum_j (attn/max(nrm,1e-12)) * vv (bf16 attn in; norm2 fused)
__global__ __launch_bounds__(256) void k_agg(const u16* __restrict__ attnb,
                                             const float* __restrict__ npart,
                                             const u16* __restrict__ vvb,
                                             u16* __restrict__ agghi,
                                             u16* __restrict__ agglo)
{
    const int it = blockIdx.x, h = blockIdx.y, b = blockIdx.z, t = threadIdx.x;
    const int d = t & 63, si = t >> 6;
    const int i = it * 4 + si;
    __shared__ float rn[KNN * DH];
    const size_t nb = (size_t)(b * HH + h) * (KNN * DH);
    for (int v = t; v < KNN * DH; v += 256) {
        float s = 0.0f;
        #pragma unroll
        for (int ic = 0; ic < 8; ++ic) s += npart[nb + v + 16384 * ic];
        rn[v] = 1.0f / fmaxf(sqrtf(s), 1e-12f);
    }
    __syncthreads();
    const u16* ab = attnb + (((size_t)(b * HH + h) * NPT + i) * KNN) * DH + d;
    const u16* vb = vvb   + (((size_t)(b * HH + h) * NPT + i) * KNN) * DH + d;
    float acc = 0.0f;
    #pragma unroll
    for (int j = 0; j < KNN; ++j) {
        float a  = bf2f(ab[j * DH]);
        float vv = bf2f(vb[j * DH]);
        acc = fmaf(a * rn[j * DH + d], vv, acc);
    }
    size_t off = ((size_t)b * NPT + i) * INNER + h * DH + d;
    u16 hi, lo; split2(acc, hi, lo);
    agghi[off] = hi;
    agglo[off] = lo;
}

// ---- K6: MFMA out GEMM (verified): out = agg @ w_out + b_out.
__global__ __launch_bounds__(256) void k_outM(const u16* __restrict__ agghi, const u16* __restrict__ agglo,
                                              const u16* __restrict__ wth, const u16* __restrict__ wtl,
                                              const float* __restrict__ bout,
                                              float* __restrict__ outp)
{
    __shared__ u16 S[4][64 * 40];
    const int t = threadIdx.x, l = t & 63, w = t >> 6;
    const int lm = l & 15, lg = (l >> 4) * 8;
    const int g0 = blockIdx.x * 64, c0 = blockIdx.y * 64;
    const int sr = t >> 2, sc = (t & 3) * 8;

    f32x4 acc[4] = {{0,0,0,0},{0,0,0,0},{0,0,0,0},{0,0,0,0}};
    float bv4[4];
    #pragma unroll
    for (int ct = 0; ct < 4; ++ct) bv4[ct] = bout[c0 + ct * 16 + lm];

    for (int ks = 0; ks < 16; ++ks) {
        const int k0 = ks * 32;
        if (ks) __syncthreads();
        *(uint4*)&S[0][sr * 40 + sc] = *(const uint4*)&agghi[(size_t)(g0 + sr) * 512 + k0 + sc];
        *(uint4*)&S[1][sr * 40 + sc] = *(const uint4*)&agglo[(size_t)(g0 + sr) * 512 + k0 + sc];
        *(uint4*)&S[2][sr * 40 + sc] = *(const uint4*)&wth[(size_t)(c0 + sr) * 512 + k0 + sc];
        *(uint4*)&S[3][sr * 40 + sc] = *(const uint4*)&wtl[(size_t)(c0 + sr) * 512 + k0 + sc];
        __syncthreads();

        const int ao = (w * 16 + lm) * 40 + lg;
        bf16x8 ah = *(const bf16x8*)&S[0][ao];
        bf16x8 al = *(const bf16x8*)&S[1][ao];
        #pragma unroll
        for (int ct = 0; ct < 4; ++ct) {
            const int bo = (ct * 16 + lm) * 40 + lg;
            bf16x8 bh = *(const bf16x8*)&S[2][bo];
            bf16x8 bl = *(const bf16x8*)&S[3][bo];
            acc[ct] = __builtin_amdgcn_mfma_f32_16x16x32_bf16(ah, bh, acc[ct], 0, 0, 0);
            acc[ct] = __builtin_amdgcn_mfma_f32_16x16x32_bf16(al, bh, acc[ct], 0, 0, 0);
            acc[ct] = __builtin_amdgcn_mfma_f32_16x16x32_bf16(ah, bl, acc[ct], 0, 0, 0);
        }
    }
    #pragma unroll
    for (int ct = 0; ct < 4; ++ct) {
        #pragma unroll
        for (int r = 0; r < 4; ++r) {
            int g = g0 + w * 16 + (l >> 4) * 4 + r;
            outp[(size_t)g * 512 + c0 + ct * 16 + lm] = acc[ct][r] + bv4[ct];
        }
    }
}

extern "C" void kernel_launch(void* const* d_in, const int* in_sizes, int n_in,
                              void* d_out, int out_size, void* d_ws, size_t ws_size,
                              hipStream_t stream) {
    const float* query     = (const float*)d_in[0];
    const float* key_in    = (const float*)d_in[1];
    const float* value     = (const float*)d_in[2];
    const float* canonical = (const float*)d_in[3];
    const float* wq   = (const float*)d_in[4];
    const float* wk   = (const float*)d_in[5];
    const float* wv   = (const float*)d_in[6];
    const float* wout = (const float*)d_in[7];
    const float* bout = (const float*)d_in[8];
    const float* pw1  = (const float*)d_in[9];
    const float* pb1  = (const float*)d_in[10];
    const float* pw2  = (const float*)d_in[11];
    const float* pb2  = (const float*)d_in[12];
    const float* aw1  = (const float*)d_in[13];
    const float* ab1  = (const float*)d_in[14];
    const float* aw2  = (const float*)d_in[15];
    const float* ab2  = (const float*)d_in[16];

    float* ws    = (float*)d_ws;
    float* Dws   = ws;                    // 1,048,576 f
    float* Vws   = ws + 1048576;          // 1,048,576 f
    float* aggp  = ws + 2097152;          // 1,048,576 f (agg hi/lo u16 planes)
    float* npart = ws + 3162112;          // 131,072 f
    int*   nbr   = (int*)(ws + 3293184);  // 32,768 i32
    float* attnR = ws + 3325952;          // 16,777,216 f region

    u16* agghi = (u16*)aggp;              // 1,048,576 u16
    u16* agglo = agghi + 1048576;

    // pre-split planes alias the attn region's TAIL; bf16 attn uses the HEAD.
    // attnb: 16,777,216 u16 = first 8,388,608 floats of the region.
    u16* attnb = (u16*)attnR;
    u16* pl   = (u16*)(attnR + 8388608);  // planes live in second half
    u16* qhi  = pl;                u16* qlo  = pl + 1048576;
    u16* khi  = pl + 2097152;      u16* klo  = pl + 3145728;
    u16* vhi  = pl + 4194304;      u16* vlo  = pl + 5242880;
    u16* wqTh = pl + 6291456;      u16* wqTl = pl + 6553600;
    u16* wkTh = pl + 6815744;      u16* wkTl = pl + 7077888;
    u16* wvTh = pl + 7340032;      u16* wvTl = pl + 7602176;  // end 7,864,320 u16 < 8,388,608

    u16* u16b  = (u16*)(ws + 20103168);
    u16* w1hi  = u16b;                    // 131,072 u16
    u16* w2hi  = u16b + 262144;           // 131,072 u16
    u16* rw2hi = u16b + 524288;           // 32,768 u16
    u16* vvb   = u16b + 589824;           // 16,777,216 u16
    u16* wouTh = u16b + 17367040;
    u16* wouTl = u16b + 17629184;         // end ~116 MB total ws

    k_pre<<<4224, 256, 0, stream>>>(query, key_in, value, aw1, aw2, pw2,
                                    qhi, qlo, khi, klo, vhi, vlo, w1hi, w2hi, rw2hi);
    k_split_T<<<dim3(8, 8, 4), 256, 0, stream>>>(wq, wk, wv, wout,
                                                 wqTh, wqTl, wkTh, wkTl, wvTh, wvTl, wouTh, wouTl);
    k_projM<<<dim3(32, 8), 256, 0, stream>>>(qhi, qlo, khi, klo, vhi, vlo,
                                             wqTh, wqTl, wkTh, wkTl, wvTh, wvTl, Dws, Vws);
    k_knn<<<dim3(256, BS), 256, 0, stream>>>(canonical, nbr);
    k_attn<<<dim3(128, HH, BS), 256, 0, stream>>>(Dws, Vws, canonical, nbr, pw1, pb1, pb2,
                                                  ab1, ab2, w1hi, w2hi, rw2hi, vvb, attnb);
    k_norm1<<<dim3(KNN, HH, BS * 8), 256, 0, stream>>>(attnb, npart);
    k_agg<<<dim3(256, HH, BS), 256, 0, stream>>>(attnb, npart, vvb, agghi, agglo);
    k_outM<<<dim3(32, 8), 256, 0, stream>>>(agghi, agglo, wouTh, wouTl, bout, (float*)d_out);
}